// Round 1
// baseline (1699.470 us; speedup 1.0000x reference)
//
#include <hip/hip_runtime.h>
#include <hip/hip_bf16.h>

#define B_ 32
#define L_ 512
#define D_ 768
#define M_ (B_*L_)
#define NEGV (-9e15f)

typedef __hip_bfloat16 bf16;
typedef short v8s __attribute__((ext_vector_type(8)));
typedef float v4f __attribute__((ext_vector_type(4)));

static __device__ __forceinline__ unsigned short f2b(float f) {
    __hip_bfloat16 h = __float2bfloat16(f);
    return *reinterpret_cast<unsigned short*>(&h);
}

// ---------------- segment info: sep_pos, valid_len per batch ----------------
__global__ void k_seg(const int* ids, const int* pad_p, const int* sep_p, int* seg) {
    int b = blockIdx.x, t = threadIdx.x;
    __shared__ int red[256];
    int pad = *pad_p, sepid = *sep_p;
    int minsep = L_, vcount = 0;
    for (int l = t; l < L_; l += 256) {
        int id = ids[b*L_ + l];
        if (id == sepid && l < minsep) minsep = l;
        if (id != pad) vcount++;
    }
    red[t] = minsep; __syncthreads();
    for (int s = 128; s > 0; s >>= 1) { if (t < s) red[t] = min(red[t], red[t+s]); __syncthreads(); }
    int sepmin = red[0]; __syncthreads();
    red[t] = vcount; __syncthreads();
    for (int s = 128; s > 0; s >>= 1) { if (t < s) red[t] += red[t+s]; __syncthreads(); }
    if (t == 0) {
        int vlen = red[0];
        int fb = vlen / 2; if (fb < 1) fb = 1; if (fb > L_-2) fb = L_-2;
        int sep = (sepmin < L_) ? sepmin : fb;
        seg[b*2] = sep; seg[b*2+1] = vlen;
    }
}

// ---------------- cast x to bf16 ----------------
__global__ void k_cast_x(const float* __restrict__ x, bf16* __restrict__ xb) {
    int n4 = M_*D_/4;
    for (int i = blockIdx.x*blockDim.x + threadIdx.x; i < n4; i += gridDim.x*blockDim.x) {
        float4 v = reinterpret_cast<const float4*>(x)[i];
        ushort4 o;
        o.x = f2b(v.x); o.y = f2b(v.y); o.z = f2b(v.z); o.w = f2b(v.w);
        reinterpret_cast<ushort4*>(xb)[i] = o;
    }
}

// ---------------- cast+transpose 6 weights to bf16 [n][k] ----------------
__global__ void k_cast_w(const float* w0, const float* w1, const float* w2,
                         const float* w3, const float* w4, const float* w5,
                         bf16* __restrict__ wbT) {
    int widx = blockIdx.y;
    const float* W;
    switch (widx) { case 0: W=w0; break; case 1: W=w1; break; case 2: W=w2; break;
                    case 3: W=w3; break; case 4: W=w4; break; default: W=w5; }
    int o = blockIdx.x*256 + threadIdx.x;     // [0, D_*D_)
    int n = o / D_, k = o % D_;
    wbT[(size_t)widx*D_*D_ + o] = __float2bfloat16(W[(size_t)k*D_ + n]);
}

__global__ void k_bias(const float* b0, const float* b1, const float* b2,
                       const float* b3, const float* b4, const float* b5,
                       float* biasAll) {
    int t = blockIdx.x*256 + threadIdx.x;
    if (t >= 6*D_) return;
    int w = t / D_, j = t % D_;
    const float* p;
    switch (w) { case 0: p=b0; break; case 1: p=b1; break; case 2: p=b2; break;
                 case 3: p=b3; break; case 4: p=b4; break; default: p=b5; }
    biasAll[t] = p[j];
}

// ---------------- anomaly logits: one wave per row ----------------
__global__ void k_anom(const float* __restrict__ x, const float* __restrict__ Wa,
                       const float* __restrict__ ba, float* __restrict__ anom) {
    int gw = (blockIdx.x*blockDim.x + threadIdx.x) >> 6;
    int lane = threadIdx.x & 63;
    if (gw >= M_) return;
    const float* xr = x + (size_t)gw*D_;
    float s = 0.f;
    #pragma unroll
    for (int i = 0; i < D_/64; i++) s += xr[lane + 64*i] * Wa[lane + 64*i];
    #pragma unroll
    for (int m = 32; m; m >>= 1) s += __shfl_xor(s, m);
    if (lane == 0) anom[gw] = s + ba[0];
}

// ---------------- gate: masked softmax over false segment ----------------
__global__ void k_gate(const float* __restrict__ anom, const int* __restrict__ ids,
                       const int* seg, const int* pad_p, float* __restrict__ gate) {
    int b = blockIdx.x, t = threadIdx.x;
    int sep = seg[b*2]; int pad = *pad_p;
    __shared__ float red[256];
    float a0[2]; bool f0[2];
    float mx = -__builtin_inff();
    #pragma unroll
    for (int j = 0; j < 2; j++) {
        int l = t + j*256;
        bool fm = (l < sep) && (ids[b*L_+l] != pad);
        float a = anom[b*L_+l];
        f0[j] = fm; a0[j] = a;
        if (fm) mx = fmaxf(mx, a);
    }
    red[t] = mx; __syncthreads();
    for (int s = 128; s; s >>= 1) { if (t < s) red[t] = fmaxf(red[t], red[t+s]); __syncthreads(); }
    mx = red[0]; __syncthreads();
    float e[2]; float se = 0.f;
    #pragma unroll
    for (int j = 0; j < 2; j++) { e[j] = f0[j] ? __expf(a0[j]-mx) : 0.f; se += e[j]; }
    red[t] = se; __syncthreads();
    for (int s = 128; s; s >>= 1) { if (t < s) red[t] += red[t+s]; __syncthreads(); }
    se = red[0];
    float inv = 1.f / fmaxf(se, 1e-8f);
    #pragma unroll
    for (int j = 0; j < 2; j++) { int l = t + j*256; gate[b*L_+l] = e[j]*inv; }
}

// ---------------- 6 projections: qk[w] = xb @ wbT[w]^T + bias, bf16 out ----
__global__ __launch_bounds__(256) void k_proj(const bf16* __restrict__ xb,
                                              const bf16* __restrict__ wbT,
                                              const float* __restrict__ biasAll,
                                              bf16* __restrict__ qk) {
    int widx = blockIdx.z;
    int mt = blockIdx.x, nt = blockIdx.y;
    int wave = threadIdx.x >> 6, lane = threadIdx.x & 63;
    int quad = lane >> 4, l16 = lane & 15;
    int row0 = mt*64 + wave*16;
    int col0 = nt*64;
    const bf16* wT = wbT + (size_t)widx*D_*D_;
    v4f acc[4] = {{0.f,0.f,0.f,0.f},{0.f,0.f,0.f,0.f},{0.f,0.f,0.f,0.f},{0.f,0.f,0.f,0.f}};
    for (int k0 = 0; k0 < D_; k0 += 32) {
        v8s a = *reinterpret_cast<const v8s*>(xb + (size_t)(row0 + l16)*D_ + k0 + quad*8);
        #pragma unroll
        for (int c = 0; c < 4; c++) {
            v8s bf = *reinterpret_cast<const v8s*>(wT + (size_t)(col0 + c*16 + l16)*D_ + k0 + quad*8);
            acc[c] = __builtin_amdgcn_mfma_f32_16x16x32_bf16(a, bf, acc[c], 0, 0, 0);
        }
    }
    bf16* out = qk + (size_t)widx*M_*D_;
    const float* bias = biasAll + widx*D_;
    #pragma unroll
    for (int c = 0; c < 4; c++) {
        #pragma unroll
        for (int r = 0; r < 4; r++) {
            int m = quad*4 + r;
            int n = col0 + c*16 + l16;
            out[(size_t)(row0+m)*D_ + n] = __float2bfloat16(acc[c][r] + bias[n]);
        }
    }
}

// ---------------- scores + softmax + gate-weighted column accumulation ------
__global__ __launch_bounds__(256) void k_score(const bf16* __restrict__ qk,
                                               const int* __restrict__ ids,
                                               const int* __restrict__ seg,
                                               const float* __restrict__ gate,
                                               const int* pad_p,
                                               float* __restrict__ w_sup,
                                               float* __restrict__ w_rep) {
    int b = blockIdx.y;
    int rt = blockIdx.x;
    int sep = seg[b*2];
    int r0 = rt*16;
    if (r0 >= sep) return;           // rows past sep have gate==0: no contribution
    int pad = *pad_p;
    __shared__ float s1[16*512];     // sup scores; reused as partial buffer later
    __shared__ float s2[16*512];     // tanh(con) + rep scores
    int wave = threadIdx.x >> 6, lane = threadIdx.x & 63;
    int quad = lane >> 4, l16 = lane & 15;
    const float inv = 0.03608439182435161f;  // 1/sqrt(768)

    for (int h = 0; h < 3; h++) {    // 0:sup  1:con  2:rep
        const bf16* Q = qk + (size_t)(2*h)*M_*D_ + (size_t)b*L_*D_;
        const bf16* K = qk + (size_t)(2*h+1)*M_*D_ + (size_t)b*L_*D_;
        for (int ct = wave; ct < 32; ct += 4) {
            int n0 = ct*16;
            v4f acc = {0.f,0.f,0.f,0.f};
            for (int k0 = 0; k0 < D_; k0 += 32) {
                v8s a  = *reinterpret_cast<const v8s*>(Q + (size_t)(r0 + l16)*D_ + k0 + quad*8);
                v8s bb = *reinterpret_cast<const v8s*>(K + (size_t)(n0 + l16)*D_ + k0 + quad*8);
                acc = __builtin_amdgcn_mfma_f32_16x16x32_bf16(a, bb, acc, 0, 0, 0);
            }
            #pragma unroll
            for (int r = 0; r < 4; r++) {
                int m = quad*4 + r, n = n0 + l16;
                float v = acc[r]*inv;
                if (h == 0)      s1[m*512 + n] = v;
                else if (h == 1) s2[m*512 + n] = tanhf(v);
                else             s2[m*512 + n] += v;
            }
        }
        __syncthreads();
    }

    // per-row softmax over option cols; accumulate gate-weighted attn per column
    float accs[8], accr[8];
    #pragma unroll
    for (int j = 0; j < 8; j++) { accs[j] = 0.f; accr[j] = 0.f; }
    bool opt[8];
    #pragma unroll
    for (int j = 0; j < 8; j++) {
        int c = lane + 64*j;
        opt[j] = (c > sep) && (ids[b*L_+c] != pad);
    }
    for (int r = 0; r < 4; r++) {
        int m = wave*4 + r;
        int rg = r0 + m;
        float g = (rg < sep) ? gate[b*L_+rg] : 0.f;
        if (g <= 0.f) continue;                      // wave-uniform
        float sv[8], rv[8];
        float mxs = NEGV, mxr = NEGV;
        #pragma unroll
        for (int j = 0; j < 8; j++) {
            int c = lane + 64*j;
            sv[j] = opt[j] ? s1[m*512 + c] : NEGV;
            rv[j] = opt[j] ? s2[m*512 + c] : NEGV;
            mxs = fmaxf(mxs, sv[j]); mxr = fmaxf(mxr, rv[j]);
        }
        #pragma unroll
        for (int d = 32; d; d >>= 1) { mxs = fmaxf(mxs, __shfl_xor(mxs, d)); mxr = fmaxf(mxr, __shfl_xor(mxr, d)); }
        float es[8], er[8]; float ssum = 0.f, rsum = 0.f;
        #pragma unroll
        for (int j = 0; j < 8; j++) {
            es[j] = __expf(sv[j]-mxs); er[j] = __expf(rv[j]-mxr);
            ssum += es[j]; rsum += er[j];
        }
        #pragma unroll
        for (int d = 32; d; d >>= 1) { ssum += __shfl_xor(ssum, d); rsum += __shfl_xor(rsum, d); }
        float gis = g/ssum, gir = g/rsum;
        #pragma unroll
        for (int j = 0; j < 8; j++) { accs[j] += es[j]*gis; accr[j] += er[j]*gir; }
    }
    __syncthreads();          // all waves done reading s1/s2
    float* pb = s1;           // reuse as [4 waves][2][512] partials
    #pragma unroll
    for (int j = 0; j < 8; j++) {
        int c = lane + 64*j;
        pb[wave*1024 + c]       = accs[j];
        pb[wave*1024 + 512 + c] = accr[j];
    }
    __syncthreads();
    int t = threadIdx.x;
    for (int c = t; c < 512; c += 256) {
        float vs = pb[c] + pb[1024+c] + pb[2048+c] + pb[3072+c];
        float vr = pb[512+c] + pb[1536+c] + pb[2560+c] + pb[3584+c];
        atomicAdd(&w_sup[b*L_+c], vs);
        atomicAdd(&w_rep[b*L_+c], vr);
    }
}

// ---------------- final: 3 gemvs + fuse MLP + layernorm, one block/batch ----
__global__ __launch_bounds__(256) void k_final(const float* __restrict__ x,
                                               const float* __restrict__ gate,
                                               const float* __restrict__ w_rep,
                                               const float* __restrict__ w_sup,
                                               const float* __restrict__ W1, const float* __restrict__ b1,
                                               const float* __restrict__ W2, const float* __restrict__ b2,
                                               const float* __restrict__ lng, const float* __restrict__ lnb,
                                               float* __restrict__ out) {
    int b = blockIdx.x, t = threadIdx.x;
    __shared__ float gs[512], rs[512], sps[512];
    __shared__ float fused[2304];
    __shared__ float h1[768];
    __shared__ float h2s[768];
    __shared__ float red[256];
    for (int l = t; l < 512; l += 256) {
        gs[l] = gate[b*512+l]; rs[l] = w_rep[b*512+l]; sps[l] = w_sup[b*512+l];
    }
    __syncthreads();
    const float* xb_ = x + (size_t)b*512*768;
    float a0=0,a1=0,a2=0, r0=0,r1=0,r2=0, s0=0,s1v=0,s2v=0;
    for (int l = 0; l < 512; l++) {
        float g = gs[l], wr = rs[l], wv = sps[l];
        float x0 = xb_[l*768 + t], x1 = xb_[l*768 + t + 256], x2 = xb_[l*768 + t + 512];
        a0 += g*x0;  a1 += g*x1;  a2 += g*x2;
        r0 += wr*x0; r1 += wr*x1; r2 += wr*x2;
        s0 += wv*x0; s1v += wv*x1; s2v += wv*x2;
    }
    fused[t] = a0;        fused[t+256] = a1;        fused[t+512] = a2;
    fused[768+t] = r0;    fused[768+t+256] = r1;    fused[768+t+512] = r2;
    fused[1536+t] = s0;   fused[1536+t+256] = s1v;  fused[1536+t+512] = s2v;
    __syncthreads();
    {
        float c0 = b1[t], c1 = b1[t+256], c2 = b1[t+512];
        for (int i = 0; i < 2304; i++) {
            float f = fused[i];
            const float* wrow = W1 + (size_t)i*768;
            c0 += f*wrow[t]; c1 += f*wrow[t+256]; c2 += f*wrow[t+512];
        }
        h1[t] = fmaxf(c0, 0.f); h1[t+256] = fmaxf(c1, 0.f); h1[t+512] = fmaxf(c2, 0.f);
    }
    __syncthreads();
    {
        float c0 = b2[t], c1 = b2[t+256], c2 = b2[t+512];
        for (int i = 0; i < 768; i++) {
            float f = h1[i];
            const float* wrow = W2 + (size_t)i*768;
            c0 += f*wrow[t]; c1 += f*wrow[t+256]; c2 += f*wrow[t+512];
        }
        h2s[t] = c0; h2s[t+256] = c1; h2s[t+512] = c2;
    }
    __syncthreads();
    float sum = 0.f, sq = 0.f;
    for (int j = t; j < 768; j += 256) { float v = h2s[j]; sum += v; sq += v*v; }
    red[t] = sum; __syncthreads();
    for (int s = 128; s; s >>= 1) { if (t < s) red[t] += red[t+s]; __syncthreads(); }
    sum = red[0]; __syncthreads();
    red[t] = sq; __syncthreads();
    for (int s = 128; s; s >>= 1) { if (t < s) red[t] += red[t+s]; __syncthreads(); }
    sq = red[0];
    float mu = sum / 768.f;
    float var = sq / 768.f - mu*mu;
    float rstd = rsqrtf(var + 1e-5f);
    for (int j = t; j < 768; j += 256) {
        out[b*768 + j] = (h2s[j]-mu)*rstd*lng[j] + lnb[j];
    }
}

extern "C" void kernel_launch(void* const* d_in, const int* in_sizes, int n_in,
                              void* d_out, int out_size, void* d_ws, size_t ws_size,
                              hipStream_t stream) {
    const float* x      = (const float*)d_in[0];
    const int*   ids    = (const int*)d_in[1];
    const int*   pad_p  = (const int*)d_in[2];
    const int*   sep_p  = (const int*)d_in[3];
    const float* W_anom = (const float*)d_in[4];
    const float* b_anom = (const float*)d_in[5];
    const float* Wq_sup = (const float*)d_in[6];  const float* bq_sup = (const float*)d_in[7];
    const float* Wk_sup = (const float*)d_in[8];  const float* bk_sup = (const float*)d_in[9];
    const float* Wq_con = (const float*)d_in[10]; const float* bq_con = (const float*)d_in[11];
    const float* Wk_con = (const float*)d_in[12]; const float* bk_con = (const float*)d_in[13];
    const float* Wq_rep = (const float*)d_in[14]; const float* bq_rep = (const float*)d_in[15];
    const float* Wk_rep = (const float*)d_in[16]; const float* bk_rep = (const float*)d_in[17];
    const float* W1     = (const float*)d_in[18]; const float* b1     = (const float*)d_in[19];
    const float* W2     = (const float*)d_in[20]; const float* b2     = (const float*)d_in[21];
    const float* lng    = (const float*)d_in[22]; const float* lnb    = (const float*)d_in[23];
    float* out = (float*)d_out;

    char* w = (char*)d_ws;
    bf16*  xb      = (bf16*)(w);                       // 25,165,824 B
    bf16*  wbT     = (bf16*)(w + 25165824);            //  7,077,888 B
    float* biasAll = (float*)(w + 32243712);           //     18,432 B
    bf16*  qk      = (bf16*)(w + 32262144);            // 150,994,944 B
    float* anom    = (float*)(w + 183257088);          //     65,536 B
    float* gate    = (float*)(w + 183322624);          //     65,536 B
    float* wsup    = (float*)(w + 183388160);          //     65,536 B
    float* wrep    = (float*)(w + 183453696);          //     65,536 B
    int*   seg     = (int*)  (w + 183519232);          //        256 B

    k_seg<<<B_, 256, 0, stream>>>(ids, pad_p, sep_p, seg);
    k_cast_x<<<4096, 256, 0, stream>>>(x, xb);
    k_cast_w<<<dim3(D_*D_/256, 6), 256, 0, stream>>>(Wq_sup, Wk_sup, Wq_con, Wk_con, Wq_rep, Wk_rep, wbT);
    k_bias<<<18, 256, 0, stream>>>(bq_sup, bk_sup, bq_con, bk_con, bq_rep, bk_rep, biasAll);
    k_anom<<<M_/4, 256, 0, stream>>>(x, W_anom, b_anom, anom);
    k_gate<<<B_, 256, 0, stream>>>(anom, ids, seg, pad_p, gate);
    hipMemsetAsync(wsup, 0, 2*B_*L_*sizeof(float), stream);   // wsup+wrep contiguous
    k_proj<<<dim3(M_/64, D_/64, 6), 256, 0, stream>>>(xb, wbT, biasAll, qk);
    k_score<<<dim3(L_/16, B_), 256, 0, stream>>>(qk, ids, seg, gate, pad_p, wsup, wrep);
    k_final<<<B_, 256, 0, stream>>>(x, gate, wrep, wsup, W1, b1, W2, b2, lng, lnb, out);
}

// Round 2
// 877.514 us; speedup vs baseline: 1.9367x; 1.9367x over previous
//
#include <hip/hip_runtime.h>
#include <hip/hip_bf16.h>

#define B_ 32
#define L_ 512
#define D_ 768
#define M_ (B_*L_)
#define NEGV (-9e15f)

typedef __hip_bfloat16 bf16;
typedef short v8s __attribute__((ext_vector_type(8)));
typedef float v4f __attribute__((ext_vector_type(4)));

static __device__ __forceinline__ unsigned short f2b(float f) {
    __hip_bfloat16 h = __float2bfloat16(f);
    return *reinterpret_cast<unsigned short*>(&h);
}

// async global->LDS, 16B per lane; lds dest is wave-uniform base, HW scatters lane i at base+i*16
static __device__ __forceinline__ void gl_lds16(const void* g, void* l) {
    __builtin_amdgcn_global_load_lds(
        (const __attribute__((address_space(1))) unsigned int*)g,
        (__attribute__((address_space(3))) unsigned int*)l, 16, 0, 0);
}

// ---------------- segment info: sep_pos, valid_len per batch ----------------
__global__ void k_seg(const int* ids, const int* pad_p, const int* sep_p, int* seg) {
    int b = blockIdx.x, t = threadIdx.x;
    __shared__ int red[256];
    int pad = *pad_p, sepid = *sep_p;
    int minsep = L_, vcount = 0;
    for (int l = t; l < L_; l += 256) {
        int id = ids[b*L_ + l];
        if (id == sepid && l < minsep) minsep = l;
        if (id != pad) vcount++;
    }
    red[t] = minsep; __syncthreads();
    for (int s = 128; s > 0; s >>= 1) { if (t < s) red[t] = min(red[t], red[t+s]); __syncthreads(); }
    int sepmin = red[0]; __syncthreads();
    red[t] = vcount; __syncthreads();
    for (int s = 128; s > 0; s >>= 1) { if (t < s) red[t] += red[t+s]; __syncthreads(); }
    if (t == 0) {
        int vlen = red[0];
        int fb = vlen / 2; if (fb < 1) fb = 1; if (fb > L_-2) fb = L_-2;
        int sep = (sepmin < L_) ? sepmin : fb;
        seg[b*2] = sep; seg[b*2+1] = vlen;
    }
}

// ---------------- cast x to bf16 ----------------
__global__ void k_cast_x(const float* __restrict__ x, bf16* __restrict__ xb) {
    int n4 = M_*D_/4;
    for (int i = blockIdx.x*blockDim.x + threadIdx.x; i < n4; i += gridDim.x*blockDim.x) {
        float4 v = reinterpret_cast<const float4*>(x)[i];
        ushort4 o;
        o.x = f2b(v.x); o.y = f2b(v.y); o.z = f2b(v.z); o.w = f2b(v.w);
        reinterpret_cast<ushort4*>(xb)[i] = o;
    }
}

// ------- cast+transpose 6 weights to bf16 [n][k], LDS-tiled (coalesced both ways) -------
__global__ __launch_bounds__(256) void k_cast_w(const float* w0, const float* w1, const float* w2,
                         const float* w3, const float* w4, const float* w5,
                         bf16* __restrict__ wbT) {
    int widx = blockIdx.z;
    const float* W;
    switch (widx) { case 0: W=w0; break; case 1: W=w1; break; case 2: W=w2; break;
                    case 3: W=w3; break; case 4: W=w4; break; default: W=w5; }
    __shared__ float tile[64][65];
    int t = threadIdx.x;
    int tr = t >> 6, tc = t & 63;        // 4 rows-groups x 64 cols
    int n0 = blockIdx.x*64, k0 = blockIdx.y*64;
    #pragma unroll
    for (int i = tr; i < 64; i += 4)     // read W[k][n], coalesced in n
        tile[i][tc] = W[(size_t)(k0+i)*D_ + n0 + tc];
    __syncthreads();
    bf16* dst = wbT + (size_t)widx*D_*D_;
    #pragma unroll
    for (int i = tr; i < 64; i += 4)     // write wbT[n][k], coalesced in k
        dst[(size_t)(n0+i)*D_ + k0 + tc] = __float2bfloat16(tile[tc][i]);
}

__global__ void k_bias(const float* b0, const float* b1, const float* b2,
                       const float* b3, const float* b4, const float* b5,
                       float* biasAll) {
    int t = blockIdx.x*256 + threadIdx.x;
    if (t >= 6*D_) return;
    int w = t / D_, j = t % D_;
    const float* p;
    switch (w) { case 0: p=b0; break; case 1: p=b1; break; case 2: p=b2; break;
                 case 3: p=b3; break; case 4: p=b4; break; default: p=b5; }
    biasAll[t] = p[j];
}

// ---------------- anomaly logits: one wave per row ----------------
__global__ void k_anom(const float* __restrict__ x, const float* __restrict__ Wa,
                       const float* __restrict__ ba, float* __restrict__ anom) {
    int gw = (blockIdx.x*blockDim.x + threadIdx.x) >> 6;
    int lane = threadIdx.x & 63;
    if (gw >= M_) return;
    const float* xr = x + (size_t)gw*D_;
    float s = 0.f;
    #pragma unroll
    for (int i = 0; i < D_/64; i++) s += xr[lane + 64*i] * Wa[lane + 64*i];
    #pragma unroll
    for (int m = 32; m; m >>= 1) s += __shfl_xor(s, m);
    if (lane == 0) anom[gw] = s + ba[0];
}

// ---------------- gate: masked softmax over false segment ----------------
__global__ void k_gate(const float* __restrict__ anom, const int* __restrict__ ids,
                       const int* seg, const int* pad_p, float* __restrict__ gate) {
    int b = blockIdx.x, t = threadIdx.x;
    int sep = seg[b*2]; int pad = *pad_p;
    __shared__ float red[256];
    float a0[2]; bool f0[2];
    float mx = -__builtin_inff();
    #pragma unroll
    for (int j = 0; j < 2; j++) {
        int l = t + j*256;
        bool fm = (l < sep) && (ids[b*L_+l] != pad);
        float a = anom[b*L_+l];
        f0[j] = fm; a0[j] = a;
        if (fm) mx = fmaxf(mx, a);
    }
    red[t] = mx; __syncthreads();
    for (int s = 128; s; s >>= 1) { if (t < s) red[t] = fmaxf(red[t], red[t+s]); __syncthreads(); }
    mx = red[0]; __syncthreads();
    float e[2]; float se = 0.f;
    #pragma unroll
    for (int j = 0; j < 2; j++) { e[j] = f0[j] ? __expf(a0[j]-mx) : 0.f; se += e[j]; }
    red[t] = se; __syncthreads();
    for (int s = 128; s; s >>= 1) { if (t < s) red[t] += red[t+s]; __syncthreads(); }
    se = red[0];
    float inv = 1.f / fmaxf(se, 1e-8f);
    #pragma unroll
    for (int j = 0; j < 2; j++) { int l = t + j*256; gate[b*L_+l] = e[j]*inv; }
}

// -------- fused projections as one GEMM: [16384 x 4608] = xb @ wbTall^T ----
// m97 structure: 128x128 tile, 4 waves (2x2), each wave 64x64 = 4x4 MFMA tiles,
// BK=32, global_load_lds width=16 staging, 2-barrier K-loop.
__global__ __launch_bounds__(256) void k_proj(const bf16* __restrict__ xb,
                                              const bf16* __restrict__ wbT,
                                              const float* __restrict__ biasAll,
                                              bf16* __restrict__ qk) {
    __shared__ bf16 As[128*32];   // [row][k] 8 KB
    __shared__ bf16 Bs[128*32];   // [n][k]   8 KB
    int t = threadIdx.x;
    int wave = t >> 6, lane = t & 63;
    int quad = lane >> 4, l16 = lane & 15;
    int wm = wave >> 1, wn = wave & 1;          // 2x2 wave grid
    int row0 = blockIdx.x * 128;
    int gn0  = blockIdx.y * 128;

    v4f acc[4][4];
    #pragma unroll
    for (int i = 0; i < 4; i++)
        #pragma unroll
        for (int j = 0; j < 4; j++) acc[i][j] = (v4f){0.f,0.f,0.f,0.f};

    // staging addresses: chunk = 16 rows x 32 k (1024 B); wave handles 2 A + 2 B chunks
    int srow = lane >> 2;            // 0..15 within chunk
    int skoff = (lane & 3) * 8;      // bf16 elems
    const bf16* agp0 = xb  + (size_t)(row0 + wave*32 + srow)*D_ + skoff;
    const bf16* agp1 = agp0 + 16*D_;
    const bf16* bgp0 = wbT + (size_t)(gn0 + wave*32 + srow)*D_ + skoff;
    const bf16* bgp1 = bgp0 + 16*D_;
    bf16* al0 = &As[(wave*2    )*512];
    bf16* al1 = &As[(wave*2 + 1)*512];
    bf16* bl0 = &Bs[(wave*2    )*512];
    bf16* bl1 = &Bs[(wave*2 + 1)*512];

    for (int k0 = 0; k0 < D_; k0 += 32) {
        gl_lds16(agp0 + k0, al0);
        gl_lds16(agp1 + k0, al1);
        gl_lds16(bgp0 + k0, bl0);
        gl_lds16(bgp1 + k0, bl1);
        __syncthreads();
        v8s af[4], bf[4];
        #pragma unroll
        for (int i = 0; i < 4; i++)
            af[i] = *reinterpret_cast<const v8s*>(&As[(wm*64 + i*16 + l16)*32 + quad*8]);
        #pragma unroll
        for (int j = 0; j < 4; j++)
            bf[j] = *reinterpret_cast<const v8s*>(&Bs[(wn*64 + j*16 + l16)*32 + quad*8]);
        #pragma unroll
        for (int i = 0; i < 4; i++)
            #pragma unroll
            for (int j = 0; j < 4; j++)
                acc[i][j] = __builtin_amdgcn_mfma_f32_16x16x32_bf16(af[i], bf[j], acc[i][j], 0, 0, 0);
        __syncthreads();
    }

    // epilogue: bias + cast + store.  gn0 block lies inside one weight (768 = 6*128)
    int widx = blockIdx.y / 6;
    int nw0  = (blockIdx.y % 6) * 128;
    bf16* out = qk + (size_t)widx*M_*D_;
    float bias[4];
    #pragma unroll
    for (int j = 0; j < 4; j++) bias[j] = biasAll[gn0 + wn*64 + j*16 + l16];
    #pragma unroll
    for (int i = 0; i < 4; i++) {
        #pragma unroll
        for (int j = 0; j < 4; j++) {
            int n = nw0 + wn*64 + j*16 + l16;
            #pragma unroll
            for (int r = 0; r < 4; r++) {
                int m = row0 + wm*64 + i*16 + quad*4 + r;
                out[(size_t)m*D_ + n] = __float2bfloat16(acc[i][j][r] + bias[j]);
            }
        }
    }
}

// ---------------- scores + softmax + gate-weighted column accumulation ------
__global__ __launch_bounds__(256) void k_score(const bf16* __restrict__ qk,
                                               const int* __restrict__ ids,
                                               const int* __restrict__ seg,
                                               const float* __restrict__ gate,
                                               const int* pad_p,
                                               float* __restrict__ w_sup,
                                               float* __restrict__ w_rep) {
    int b = blockIdx.y;
    int rt = blockIdx.x;
    int sep = seg[b*2];
    int r0 = rt*16;
    if (r0 >= sep) return;           // rows past sep have gate==0: no contribution
    int pad = *pad_p;
    __shared__ float s1[16*512];     // sup scores; reused as partial buffer later
    __shared__ float s2[16*512];     // tanh(con) + rep scores
    int wave = threadIdx.x >> 6, lane = threadIdx.x & 63;
    int quad = lane >> 4, l16 = lane & 15;
    const float inv = 0.03608439182435161f;  // 1/sqrt(768)

    for (int h = 0; h < 3; h++) {    // 0:sup  1:con  2:rep
        const bf16* Q = qk + (size_t)(2*h)*M_*D_ + (size_t)b*L_*D_;
        const bf16* K = qk + (size_t)(2*h+1)*M_*D_ + (size_t)b*L_*D_;
        for (int ct = wave; ct < 32; ct += 4) {
            int n0 = ct*16;
            v4f acc = {0.f,0.f,0.f,0.f};
            for (int k0 = 0; k0 < D_; k0 += 32) {
                v8s a  = *reinterpret_cast<const v8s*>(Q + (size_t)(r0 + l16)*D_ + k0 + quad*8);
                v8s bb = *reinterpret_cast<const v8s*>(K + (size_t)(n0 + l16)*D_ + k0 + quad*8);
                acc = __builtin_amdgcn_mfma_f32_16x16x32_bf16(a, bb, acc, 0, 0, 0);
            }
            #pragma unroll
            for (int r = 0; r < 4; r++) {
                int m = quad*4 + r, n = n0 + l16;
                float v = acc[r]*inv;
                if (h == 0)      s1[m*512 + n] = v;
                else if (h == 1) s2[m*512 + n] = tanhf(v);
                else             s2[m*512 + n] += v;
            }
        }
        __syncthreads();
    }

    // per-row softmax over option cols; accumulate gate-weighted attn per column
    float accs[8], accr[8];
    #pragma unroll
    for (int j = 0; j < 8; j++) { accs[j] = 0.f; accr[j] = 0.f; }
    bool opt[8];
    #pragma unroll
    for (int j = 0; j < 8; j++) {
        int c = lane + 64*j;
        opt[j] = (c > sep) && (ids[b*L_+c] != pad);
    }
    for (int r = 0; r < 4; r++) {
        int m = wave*4 + r;
        int rg = r0 + m;
        float g = (rg < sep) ? gate[b*L_+rg] : 0.f;
        if (g <= 0.f) continue;                      // wave-uniform
        float sv[8], rv[8];
        float mxs = NEGV, mxr = NEGV;
        #pragma unroll
        for (int j = 0; j < 8; j++) {
            int c = lane + 64*j;
            sv[j] = opt[j] ? s1[m*512 + c] : NEGV;
            rv[j] = opt[j] ? s2[m*512 + c] : NEGV;
            mxs = fmaxf(mxs, sv[j]); mxr = fmaxf(mxr, rv[j]);
        }
        #pragma unroll
        for (int d = 32; d; d >>= 1) { mxs = fmaxf(mxs, __shfl_xor(mxs, d)); mxr = fmaxf(mxr, __shfl_xor(mxr, d)); }
        float es[8], er[8]; float ssum = 0.f, rsum = 0.f;
        #pragma unroll
        for (int j = 0; j < 8; j++) {
            es[j] = __expf(sv[j]-mxs); er[j] = __expf(rv[j]-mxr);
            ssum += es[j]; rsum += er[j];
        }
        #pragma unroll
        for (int d = 32; d; d >>= 1) { ssum += __shfl_xor(ssum, d); rsum += __shfl_xor(rsum, d); }
        float gis = g/ssum, gir = g/rsum;
        #pragma unroll
        for (int j = 0; j < 8; j++) { accs[j] += es[j]*gis; accr[j] += er[j]*gir; }
    }
    __syncthreads();          // all waves done reading s1/s2
    float* pb = s1;           // reuse as [4 waves][2][512] partials
    #pragma unroll
    for (int j = 0; j < 8; j++) {
        int c = lane + 64*j;
        pb[wave*1024 + c]       = accs[j];
        pb[wave*1024 + 512 + c] = accr[j];
    }
    __syncthreads();
    int t = threadIdx.x;
    for (int c = t; c < 512; c += 256) {
        float vs = pb[c] + pb[1024+c] + pb[2048+c] + pb[3072+c];
        float vr = pb[512+c] + pb[1536+c] + pb[2560+c] + pb[3584+c];
        atomicAdd(&w_sup[b*L_+c], vs);
        atomicAdd(&w_rep[b*L_+c], vr);
    }
}

// ---------------- final: 3 gemvs + fuse MLP + layernorm, one block/batch ----
__global__ __launch_bounds__(256) void k_final(const float* __restrict__ x,
                                               const float* __restrict__ gate,
                                               const float* __restrict__ w_rep,
                                               const float* __restrict__ w_sup,
                                               const float* __restrict__ W1, const float* __restrict__ b1,
                                               const float* __restrict__ W2, const float* __restrict__ b2,
                                               const float* __restrict__ lng, const float* __restrict__ lnb,
                                               float* __restrict__ out) {
    int b = blockIdx.x, t = threadIdx.x;
    __shared__ float gs[512], rs[512], sps[512];
    __shared__ float fused[2304];
    __shared__ float h1[768];
    __shared__ float h2s[768];
    __shared__ float red[256];
    for (int l = t; l < 512; l += 256) {
        gs[l] = gate[b*512+l]; rs[l] = w_rep[b*512+l]; sps[l] = w_sup[b*512+l];
    }
    __syncthreads();
    const float* xb_ = x + (size_t)b*512*768;
    float a0=0,a1=0,a2=0, r0=0,r1=0,r2=0, s0=0,s1v=0,s2v=0;
    for (int l = 0; l < 512; l++) {
        float g = gs[l], wr = rs[l], wv = sps[l];
        float x0 = xb_[l*768 + t], x1 = xb_[l*768 + t + 256], x2 = xb_[l*768 + t + 512];
        a0 += g*x0;  a1 += g*x1;  a2 += g*x2;
        r0 += wr*x0; r1 += wr*x1; r2 += wr*x2;
        s0 += wv*x0; s1v += wv*x1; s2v += wv*x2;
    }
    fused[t] = a0;        fused[t+256] = a1;        fused[t+512] = a2;
    fused[768+t] = r0;    fused[768+t+256] = r1;    fused[768+t+512] = r2;
    fused[1536+t] = s0;   fused[1536+t+256] = s1v;  fused[1536+t+512] = s2v;
    __syncthreads();
    {
        float c0 = b1[t], c1 = b1[t+256], c2 = b1[t+512];
        for (int i = 0; i < 2304; i++) {
            float f = fused[i];
            const float* wrow = W1 + (size_t)i*768;
            c0 += f*wrow[t]; c1 += f*wrow[t+256]; c2 += f*wrow[t+512];
        }
        h1[t] = fmaxf(c0, 0.f); h1[t+256] = fmaxf(c1, 0.f); h1[t+512] = fmaxf(c2, 0.f);
    }
    __syncthreads();
    {
        float c0 = b2[t], c1 = b2[t+256], c2 = b2[t+512];
        for (int i = 0; i < 768; i++) {
            float f = h1[i];
            const float* wrow = W2 + (size_t)i*768;
            c0 += f*wrow[t]; c1 += f*wrow[t+256]; c2 += f*wrow[t+512];
        }
        h2s[t] = c0; h2s[t+256] = c1; h2s[t+512] = c2;
    }
    __syncthreads();
    float sum = 0.f, sq = 0.f;
    for (int j = t; j < 768; j += 256) { float v = h2s[j]; sum += v; sq += v*v; }
    red[t] = sum; __syncthreads();
    for (int s = 128; s; s >>= 1) { if (t < s) red[t] += red[t+s]; __syncthreads(); }
    sum = red[0]; __syncthreads();
    red[t] = sq; __syncthreads();
    for (int s = 128; s; s >>= 1) { if (t < s) red[t] += red[t+s]; __syncthreads(); }
    sq = red[0];
    float mu = sum / 768.f;
    float var = sq / 768.f - mu*mu;
    float rstd = rsqrtf(var + 1e-5f);
    for (int j = t; j < 768; j += 256) {
        out[b*768 + j] = (h2s[j]-mu)*rstd*lng[j] + lnb[j];
    }
}

extern "C" void kernel_launch(void* const* d_in, const int* in_sizes, int n_in,
                              void* d_out, int out_size, void* d_ws, size_t ws_size,
                              hipStream_t stream) {
    const float* x      = (const float*)d_in[0];
    const int*   ids    = (const int*)d_in[1];
    const int*   pad_p  = (const int*)d_in[2];
    const int*   sep_p  = (const int*)d_in[3];
    const float* W_anom = (const float*)d_in[4];
    const float* b_anom = (const float*)d_in[5];
    const float* Wq_sup = (const float*)d_in[6];  const float* bq_sup = (const float*)d_in[7];
    const float* Wk_sup = (const float*)d_in[8];  const float* bk_sup = (const float*)d_in[9];
    const float* Wq_con = (const float*)d_in[10]; const float* bq_con = (const float*)d_in[11];
    const float* Wk_con = (const float*)d_in[12]; const float* bk_con = (const float*)d_in[13];
    const float* Wq_rep = (const float*)d_in[14]; const float* bq_rep = (const float*)d_in[15];
    const float* Wk_rep = (const float*)d_in[16]; const float* bk_rep = (const float*)d_in[17];
    const float* W1     = (const float*)d_in[18]; const float* b1     = (const float*)d_in[19];
    const float* W2     = (const float*)d_in[20]; const float* b2     = (const float*)d_in[21];
    const float* lng    = (const float*)d_in[22]; const float* lnb    = (const float*)d_in[23];
    float* out = (float*)d_out;

    char* w = (char*)d_ws;
    bf16*  xb      = (bf16*)(w);                       // 25,165,824 B
    bf16*  wbT     = (bf16*)(w + 25165824);            //  7,077,888 B  ([6*768][768] = [4608][768])
    float* biasAll = (float*)(w + 32243712);           //     18,432 B
    bf16*  qk      = (bf16*)(w + 32262144);            // 150,994,944 B
    float* anom    = (float*)(w + 183257088);          //     65,536 B
    float* gate    = (float*)(w + 183322624);          //     65,536 B
    float* wsup    = (float*)(w + 183388160);          //     65,536 B
    float* wrep    = (float*)(w + 183453696);          //     65,536 B
    int*   seg     = (int*)  (w + 183519232);          //        256 B

    k_seg<<<B_, 256, 0, stream>>>(ids, pad_p, sep_p, seg);
    k_cast_x<<<4096, 256, 0, stream>>>(x, xb);
    k_cast_w<<<dim3(D_/64, D_/64, 6), 256, 0, stream>>>(Wq_sup, Wk_sup, Wq_con, Wk_con, Wq_rep, Wk_rep, wbT);
    k_bias<<<18, 256, 0, stream>>>(bq_sup, bk_sup, bq_con, bk_con, bq_rep, bk_rep, biasAll);
    k_anom<<<M_/4, 256, 0, stream>>>(x, W_anom, b_anom, anom);
    k_gate<<<B_, 256, 0, stream>>>(anom, ids, seg, pad_p, gate);
    hipMemsetAsync(wsup, 0, 2*B_*L_*sizeof(float), stream);   // wsup+wrep contiguous
    k_proj<<<dim3(M_/128, 6*D_/128), 256, 0, stream>>>(xb, wbT, biasAll, qk);
    k_score<<<dim3(L_/16, B_), 256, 0, stream>>>(qk, ids, seg, gate, pad_p, wsup, wrep);
    k_final<<<B_, 256, 0, stream>>>(x, gate, wrep, wsup, W1, b1, W2, b2, lng, lnb, out);
}

// Round 3
// 767.626 us; speedup vs baseline: 2.2139x; 1.1432x over previous
//
#include <hip/hip_runtime.h>
#include <hip/hip_bf16.h>

#define B_ 32
#define L_ 512
#define D_ 768
#define M_ (B_*L_)
#define NEGV (-9e15f)

typedef __hip_bfloat16 bf16;
typedef short v8s __attribute__((ext_vector_type(8)));
typedef float v4f __attribute__((ext_vector_type(4)));

static __device__ __forceinline__ unsigned short f2b(float f) {
    __hip_bfloat16 h = __float2bfloat16(f);
    return *reinterpret_cast<unsigned short*>(&h);
}

static __device__ __forceinline__ float fast_tanh(float x) {
    x = fminf(fmaxf(x, -15.f), 15.f);
    float e2 = __expf(2.f * x);
    return (e2 - 1.f) / (e2 + 1.f);
}

// async global->LDS, 16B per lane; lds dest is wave-uniform base, HW scatters lane i at base+i*16
static __device__ __forceinline__ void gl_lds16(const void* g, void* l) {
    __builtin_amdgcn_global_load_lds(
        (const __attribute__((address_space(1))) unsigned int*)g,
        (__attribute__((address_space(3))) unsigned int*)l, 16, 0, 0);
}

// ---------------- segment info: sep_pos, valid_len per batch ----------------
__global__ void k_seg(const int* ids, const int* pad_p, const int* sep_p, int* seg) {
    int b = blockIdx.x, t = threadIdx.x;
    __shared__ int red[256];
    int pad = *pad_p, sepid = *sep_p;
    int minsep = L_, vcount = 0;
    for (int l = t; l < L_; l += 256) {
        int id = ids[b*L_ + l];
        if (id == sepid && l < minsep) minsep = l;
        if (id != pad) vcount++;
    }
    red[t] = minsep; __syncthreads();
    for (int s = 128; s > 0; s >>= 1) { if (t < s) red[t] = min(red[t], red[t+s]); __syncthreads(); }
    int sepmin = red[0]; __syncthreads();
    red[t] = vcount; __syncthreads();
    for (int s = 128; s > 0; s >>= 1) { if (t < s) red[t] += red[t+s]; __syncthreads(); }
    if (t == 0) {
        int vlen = red[0];
        int fb = vlen / 2; if (fb < 1) fb = 1; if (fb > L_-2) fb = L_-2;
        int sep = (sepmin < L_) ? sepmin : fb;
        seg[b*2] = sep; seg[b*2+1] = vlen;
    }
}

// ---------------- cast x to bf16 ----------------
__global__ void k_cast_x(const float* __restrict__ x, bf16* __restrict__ xb) {
    int n4 = M_*D_/4;
    for (int i = blockIdx.x*blockDim.x + threadIdx.x; i < n4; i += gridDim.x*blockDim.x) {
        float4 v = reinterpret_cast<const float4*>(x)[i];
        ushort4 o;
        o.x = f2b(v.x); o.y = f2b(v.y); o.z = f2b(v.z); o.w = f2b(v.w);
        reinterpret_cast<ushort4*>(xb)[i] = o;
    }
}

// ------- cast+transpose 6 weights to bf16 [n][k], LDS-tiled -------
__global__ __launch_bounds__(256) void k_cast_w(const float* w0, const float* w1, const float* w2,
                         const float* w3, const float* w4, const float* w5,
                         bf16* __restrict__ wbT) {
    int widx = blockIdx.z;
    const float* W;
    switch (widx) { case 0: W=w0; break; case 1: W=w1; break; case 2: W=w2; break;
                    case 3: W=w3; break; case 4: W=w4; break; default: W=w5; }
    __shared__ float tile[64][65];
    int t = threadIdx.x;
    int tr = t >> 6, tc = t & 63;
    int n0 = blockIdx.x*64, k0 = blockIdx.y*64;
    #pragma unroll
    for (int i = tr; i < 64; i += 4)
        tile[i][tc] = W[(size_t)(k0+i)*D_ + n0 + tc];
    __syncthreads();
    bf16* dst = wbT + (size_t)widx*D_*D_;
    #pragma unroll
    for (int i = tr; i < 64; i += 4)
        dst[(size_t)(n0+i)*D_ + k0 + tc] = __float2bfloat16(tile[tc][i]);
}

__global__ void k_bias(const float* b0, const float* b1, const float* b2,
                       const float* b3, const float* b4, const float* b5,
                       float* biasAll) {
    int t = blockIdx.x*256 + threadIdx.x;
    if (t >= 6*D_) return;
    int w = t / D_, j = t % D_;
    const float* p;
    switch (w) { case 0: p=b0; break; case 1: p=b1; break; case 2: p=b2; break;
                 case 3: p=b3; break; case 4: p=b4; break; default: p=b5; }
    biasAll[t] = p[j];
}

// ---------------- anomaly logits: one wave per row ----------------
__global__ void k_anom(const float* __restrict__ x, const float* __restrict__ Wa,
                       const float* __restrict__ ba, float* __restrict__ anom) {
    int gw = (blockIdx.x*blockDim.x + threadIdx.x) >> 6;
    int lane = threadIdx.x & 63;
    if (gw >= M_) return;
    const float* xr = x + (size_t)gw*D_;
    float s = 0.f;
    #pragma unroll
    for (int i = 0; i < D_/64; i++) s += xr[lane + 64*i] * Wa[lane + 64*i];
    #pragma unroll
    for (int m = 32; m; m >>= 1) s += __shfl_xor(s, m);
    if (lane == 0) anom[gw] = s + ba[0];
}

// ---------------- gate: masked softmax over false segment ----------------
__global__ void k_gate(const float* __restrict__ anom, const int* __restrict__ ids,
                       const int* seg, const int* pad_p, float* __restrict__ gate) {
    int b = blockIdx.x, t = threadIdx.x;
    int sep = seg[b*2]; int pad = *pad_p;
    __shared__ float red[256];
    float a0[2]; bool f0[2];
    float mx = -__builtin_inff();
    #pragma unroll
    for (int j = 0; j < 2; j++) {
        int l = t + j*256;
        bool fm = (l < sep) && (ids[b*L_+l] != pad);
        float a = anom[b*L_+l];
        f0[j] = fm; a0[j] = a;
        if (fm) mx = fmaxf(mx, a);
    }
    red[t] = mx; __syncthreads();
    for (int s = 128; s; s >>= 1) { if (t < s) red[t] = fmaxf(red[t], red[t+s]); __syncthreads(); }
    mx = red[0]; __syncthreads();
    float e[2]; float se = 0.f;
    #pragma unroll
    for (int j = 0; j < 2; j++) { e[j] = f0[j] ? __expf(a0[j]-mx) : 0.f; se += e[j]; }
    red[t] = se; __syncthreads();
    for (int s = 128; s; s >>= 1) { if (t < s) red[t] += red[t+s]; __syncthreads(); }
    se = red[0];
    float inv = 1.f / fmaxf(se, 1e-8f);
    #pragma unroll
    for (int j = 0; j < 2; j++) { int l = t + j*256; gate[b*L_+l] = e[j]*inv; }
}

// -------- fused projections as one GEMM: [16384 x 4608] = xb @ wbTall^T ----
__global__ __launch_bounds__(256) void k_proj(const bf16* __restrict__ xb,
                                              const bf16* __restrict__ wbT,
                                              const float* __restrict__ biasAll,
                                              bf16* __restrict__ qk) {
    __shared__ bf16 As[128*32];
    __shared__ bf16 Bs[128*32];
    int t = threadIdx.x;
    int wave = t >> 6, lane = t & 63;
    int quad = lane >> 4, l16 = lane & 15;
    int wm = wave >> 1, wn = wave & 1;
    int row0 = blockIdx.x * 128;
    int gn0  = blockIdx.y * 128;

    v4f acc[4][4];
    #pragma unroll
    for (int i = 0; i < 4; i++)
        #pragma unroll
        for (int j = 0; j < 4; j++) acc[i][j] = (v4f){0.f,0.f,0.f,0.f};

    int srow = lane >> 2;
    int skoff = (lane & 3) * 8;
    const bf16* agp0 = xb  + (size_t)(row0 + wave*32 + srow)*D_ + skoff;
    const bf16* agp1 = agp0 + 16*D_;
    const bf16* bgp0 = wbT + (size_t)(gn0 + wave*32 + srow)*D_ + skoff;
    const bf16* bgp1 = bgp0 + 16*D_;
    bf16* al0 = &As[(wave*2    )*512];
    bf16* al1 = &As[(wave*2 + 1)*512];
    bf16* bl0 = &Bs[(wave*2    )*512];
    bf16* bl1 = &Bs[(wave*2 + 1)*512];

    for (int k0 = 0; k0 < D_; k0 += 32) {
        gl_lds16(agp0 + k0, al0);
        gl_lds16(agp1 + k0, al1);
        gl_lds16(bgp0 + k0, bl0);
        gl_lds16(bgp1 + k0, bl1);
        __syncthreads();
        v8s af[4], bf[4];
        #pragma unroll
        for (int i = 0; i < 4; i++)
            af[i] = *reinterpret_cast<const v8s*>(&As[(wm*64 + i*16 + l16)*32 + quad*8]);
        #pragma unroll
        for (int j = 0; j < 4; j++)
            bf[j] = *reinterpret_cast<const v8s*>(&Bs[(wn*64 + j*16 + l16)*32 + quad*8]);
        #pragma unroll
        for (int i = 0; i < 4; i++)
            #pragma unroll
            for (int j = 0; j < 4; j++)
                acc[i][j] = __builtin_amdgcn_mfma_f32_16x16x32_bf16(af[i], bf[j], acc[i][j], 0, 0, 0);
        __syncthreads();
    }

    int widx = blockIdx.y / 6;
    int nw0  = (blockIdx.y % 6) * 128;
    bf16* out = qk + (size_t)widx*M_*D_;
    float bias[4];
    #pragma unroll
    for (int j = 0; j < 4; j++) bias[j] = biasAll[gn0 + wn*64 + j*16 + l16];
    #pragma unroll
    for (int i = 0; i < 4; i++) {
        #pragma unroll
        for (int j = 0; j < 4; j++) {
            int n = nw0 + wn*64 + j*16 + l16;
            #pragma unroll
            for (int r = 0; r < 4; r++) {
                int m = row0 + wm*64 + i*16 + quad*4 + r;
                out[(size_t)m*D_ + n] = __float2bfloat16(acc[i][j][r] + bias[j]);
            }
        }
    }
}

// ------ scores in registers: per-wave 6 col-tiles, softmax + gate-reduce ----
__global__ __launch_bounds__(256) void k_score(const bf16* __restrict__ qk,
                                               const int* __restrict__ ids,
                                               const int* __restrict__ seg,
                                               const float* __restrict__ gate,
                                               const int* pad_p,
                                               float* __restrict__ w_sup,
                                               float* __restrict__ w_rep) {
    int b = blockIdx.x, rt = blockIdx.y;          // x=batch for XCD L2 affinity
    int sep = seg[b*2];
    int r0 = rt*16;
    if (r0 >= sep) return;
    int pad = *pad_p;
    int wave = threadIdx.x >> 6, lane = threadIdx.x & 63;
    int quad = lane >> 4, l16 = lane & 15;
    const float inv  = 0.03608439182435161f;      // 1/sqrt(768)
    const float rinv = 27.712812921102035f;       // sqrt(768)
    int ct0 = (sep + 1) >> 4;                     // first tile containing cols > sep

    int tile[6]; bool act[6];
    #pragma unroll
    for (int i = 0; i < 6; i++) {
        int ctv = ct0 + wave + 4*i;
        act[i] = ctv < 32;
        tile[i] = act[i] ? ctv : 31;
    }
    int qoff = (r0 + l16)*D_ + quad*8;
    int koff[6];
    #pragma unroll
    for (int i = 0; i < 6; i++) koff[i] = (tile[i]*16 + l16)*D_ + quad*8;

    v4f S[6], R[6];
    #pragma unroll
    for (int i = 0; i < 6; i++) { S[i] = (v4f){0,0,0,0}; R[i] = (v4f){0,0,0,0}; }

    const size_t bo = (size_t)b*L_*D_;
    // --- head con (slots 2,3) into R ---
    {
        const bf16* Q = qk + (size_t)2*M_*D_ + bo;
        const bf16* K = qk + (size_t)3*M_*D_ + bo;
        for (int k0 = 0; k0 < D_; k0 += 32) {
            v8s a = *reinterpret_cast<const v8s*>(Q + qoff + k0);
            #pragma unroll
            for (int i = 0; i < 6; i++) {
                v8s kf = *reinterpret_cast<const v8s*>(K + koff[i] + k0);
                R[i] = __builtin_amdgcn_mfma_f32_16x16x32_bf16(a, kf, R[i], 0, 0, 0);
            }
        }
    }
    // R := tanh(con*inv)/inv  so that after adding rep_raw, R*inv = rep*inv + tanh
    #pragma unroll
    for (int i = 0; i < 6; i++)
        #pragma unroll
        for (int r = 0; r < 4; r++)
            R[i][r] = fast_tanh(R[i][r]*inv) * rinv;
    // --- head rep (slots 4,5) accumulates into R ---
    {
        const bf16* Q = qk + (size_t)4*M_*D_ + bo;
        const bf16* K = qk + (size_t)5*M_*D_ + bo;
        for (int k0 = 0; k0 < D_; k0 += 32) {
            v8s a = *reinterpret_cast<const v8s*>(Q + qoff + k0);
            #pragma unroll
            for (int i = 0; i < 6; i++) {
                v8s kf = *reinterpret_cast<const v8s*>(K + koff[i] + k0);
                R[i] = __builtin_amdgcn_mfma_f32_16x16x32_bf16(a, kf, R[i], 0, 0, 0);
            }
        }
    }
    // --- head sup (slots 0,1) into S ---
    {
        const bf16* Q = qk + bo;
        const bf16* K = qk + (size_t)M_*D_ + bo;
        for (int k0 = 0; k0 < D_; k0 += 32) {
            v8s a = *reinterpret_cast<const v8s*>(Q + qoff + k0);
            #pragma unroll
            for (int i = 0; i < 6; i++) {
                v8s kf = *reinterpret_cast<const v8s*>(K + koff[i] + k0);
                S[i] = __builtin_amdgcn_mfma_f32_16x16x32_bf16(a, kf, S[i], 0, 0, 0);
            }
        }
    }

    bool opt[6];
    #pragma unroll
    for (int i = 0; i < 6; i++) {
        int c = tile[i]*16 + l16;
        opt[i] = act[i] && (c > sep) && (ids[b*L_ + c] != pad);
    }

    // per-row max (rows quad*4+r owned by this quad's 16 lanes)
    float mxs[4], mxr[4];
    #pragma unroll
    for (int r = 0; r < 4; r++) { mxs[r] = NEGV; mxr[r] = NEGV; }
    #pragma unroll
    for (int i = 0; i < 6; i++)
        #pragma unroll
        for (int r = 0; r < 4; r++) {
            if (1) {
                float sv = opt[i] ? S[i][r]*inv : NEGV;
                float rv = opt[i] ? R[i][r]*inv : NEGV;
                mxs[r] = fmaxf(mxs[r], sv);
                mxr[r] = fmaxf(mxr[r], rv);
            }
        }
    #pragma unroll
    for (int d = 1; d < 16; d <<= 1)
        #pragma unroll
        for (int r = 0; r < 4; r++) {
            mxs[r] = fmaxf(mxs[r], __shfl_xor(mxs[r], d));
            mxr[r] = fmaxf(mxr[r], __shfl_xor(mxr[r], d));
        }
    __shared__ float redm[2][16][4];
    __shared__ float reds[2][16][4];
    if (l16 == 0)
        #pragma unroll
        for (int r = 0; r < 4; r++) {
            redm[0][quad*4+r][wave] = mxs[r];
            redm[1][quad*4+r][wave] = mxr[r];
        }
    __syncthreads();
    #pragma unroll
    for (int r = 0; r < 4; r++) {
        int row = quad*4 + r;
        mxs[r] = fmaxf(fmaxf(redm[0][row][0], redm[0][row][1]), fmaxf(redm[0][row][2], redm[0][row][3]));
        mxr[r] = fmaxf(fmaxf(redm[1][row][0], redm[1][row][1]), fmaxf(redm[1][row][2], redm[1][row][3]));
    }

    // exp in place, row sums
    float ssum[4] = {0,0,0,0}, rsum[4] = {0,0,0,0};
    #pragma unroll
    for (int i = 0; i < 6; i++)
        #pragma unroll
        for (int r = 0; r < 4; r++) {
            float es = opt[i] ? __expf(S[i][r]*inv - mxs[r]) : 0.f;
            float er = opt[i] ? __expf(R[i][r]*inv - mxr[r]) : 0.f;
            S[i][r] = es; R[i][r] = er;
            ssum[r] += es; rsum[r] += er;
        }
    #pragma unroll
    for (int d = 1; d < 16; d <<= 1)
        #pragma unroll
        for (int r = 0; r < 4; r++) {
            ssum[r] += __shfl_xor(ssum[r], d);
            rsum[r] += __shfl_xor(rsum[r], d);
        }
    if (l16 == 0)
        #pragma unroll
        for (int r = 0; r < 4; r++) {
            reds[0][quad*4+r][wave] = ssum[r];
            reds[1][quad*4+r][wave] = rsum[r];
        }
    __syncthreads();
    float gs_[4], gr_[4];
    #pragma unroll
    for (int r = 0; r < 4; r++) {
        int row = quad*4 + r;
        float st = reds[0][row][0] + reds[0][row][1] + reds[0][row][2] + reds[0][row][3];
        float rtot = reds[1][row][0] + reds[1][row][1] + reds[1][row][2] + reds[1][row][3];
        float g = gate[b*L_ + r0 + row];
        gs_[r] = g / st;
        gr_[r] = g / rtot;
    }

    // gate-weighted column sums; butterfly across quads then atomic
    #pragma unroll
    for (int i = 0; i < 6; i++) {
        float cs = 0.f, cr = 0.f;
        #pragma unroll
        for (int r = 0; r < 4; r++) { cs += S[i][r]*gs_[r]; cr += R[i][r]*gr_[r]; }
        cs += __shfl_xor(cs, 16); cs += __shfl_xor(cs, 32);
        cr += __shfl_xor(cr, 16); cr += __shfl_xor(cr, 32);
        if (act[i] && quad == 0) {
            int c = tile[i]*16 + l16;
            atomicAdd(&w_sup[b*L_ + c], cs);
            atomicAdd(&w_rep[b*L_ + c], cr);
        }
    }
}

// ---- 3 gemvs over L: partial per 64-row chunk, atomic into fused[32][2304] --
__global__ __launch_bounds__(256) void k_fused(const float* __restrict__ x,
                                               const float* __restrict__ gate,
                                               const float* __restrict__ wrep,
                                               const float* __restrict__ wsup,
                                               float* __restrict__ fused) {
    int b = blockIdx.x, ch = blockIdx.y, t = threadIdx.x;
    int l0 = ch*64;
    const float* xb_ = x + (size_t)b*L_*D_;
    float a0=0,a1=0,a2=0, r0=0,r1=0,r2=0, s0=0,s1=0,s2=0;
    for (int l = l0; l < l0+64; l++) {
        float g = gate[b*L_+l], wr = wrep[b*L_+l], wv = wsup[b*L_+l];
        if (g == 0.f && wr == 0.f && wv == 0.f) continue;
        float x0 = xb_[l*D_ + t], x1 = xb_[l*D_ + t + 256], x2 = xb_[l*D_ + t + 512];
        a0 += g*x0;  a1 += g*x1;  a2 += g*x2;
        r0 += wr*x0; r1 += wr*x1; r2 += wr*x2;
        s0 += wv*x0; s1 += wv*x1; s2 += wv*x2;
    }
    float* f = fused + (size_t)b*2304;
    atomicAdd(&f[t],        a0); atomicAdd(&f[t+256],      a1); atomicAdd(&f[t+512],      a2);
    atomicAdd(&f[768+t],    r0); atomicAdd(&f[768+t+256],  r1); atomicAdd(&f[768+t+512],  r2);
    atomicAdd(&f[1536+t],   s0); atomicAdd(&f[1536+t+256], s1); atomicAdd(&f[1536+t+512], s2);
}

// ---- MLP layer 1: 4 batches per block share W1 reads; relu ----
__global__ __launch_bounds__(256) void k_mlp1(const float* __restrict__ fused,
                                              const float* __restrict__ W1,
                                              const float* __restrict__ b1,
                                              float* __restrict__ h1buf) {
    int bg = blockIdx.x, ch = blockIdx.y, t = threadIdx.x;
    __shared__ float fs[4*2304];
    for (int i = t; i < 4*2304; i += 256) fs[i] = fused[(size_t)bg*4*2304 + i];
    __syncthreads();
    int c = ch*256 + t;
    float bc = b1[c];
    float a0 = bc, a1 = bc, a2 = bc, a3 = bc;
    for (int i = 0; i < 2304; i++) {
        float w = W1[(size_t)i*D_ + c];
        a0 += fs[i]*w; a1 += fs[2304+i]*w; a2 += fs[4608+i]*w; a3 += fs[6912+i]*w;
    }
    h1buf[(size_t)(bg*4+0)*D_ + c] = fmaxf(a0, 0.f);
    h1buf[(size_t)(bg*4+1)*D_ + c] = fmaxf(a1, 0.f);
    h1buf[(size_t)(bg*4+2)*D_ + c] = fmaxf(a2, 0.f);
    h1buf[(size_t)(bg*4+3)*D_ + c] = fmaxf(a3, 0.f);
}

// ---- MLP layer 2 + LayerNorm: 4 batches per block ----
__global__ __launch_bounds__(256) void k_mlp2(const float* __restrict__ h1buf,
                                              const float* __restrict__ W2,
                                              const float* __restrict__ b2,
                                              const float* __restrict__ lng,
                                              const float* __restrict__ lnb,
                                              float* __restrict__ out) {
    int bg = blockIdx.x, t = threadIdx.x;
    __shared__ float hs[4*768];
    __shared__ float h2[4*768];
    __shared__ float red[256];
    for (int i = t; i < 4*768; i += 256) hs[i] = h1buf[(size_t)bg*4*768 + i];
    __syncthreads();
    for (int c3 = 0; c3 < 3; c3++) {
        int c = c3*256 + t;
        float bc = b2[c];
        float a0 = bc, a1 = bc, a2 = bc, a3 = bc;
        for (int i = 0; i < 768; i++) {
            float w = W2[(size_t)i*D_ + c];
            a0 += hs[i]*w; a1 += hs[768+i]*w; a2 += hs[1536+i]*w; a3 += hs[2304+i]*w;
        }
        h2[c] = a0; h2[768+c] = a1; h2[1536+c] = a2; h2[2304+c] = a3;
    }
    __syncthreads();
    for (int q = 0; q < 4; q++) {
        float sum = 0.f, sq = 0.f;
        for (int j = t; j < 768; j += 256) { float v = h2[q*768+j]; sum += v; sq += v*v; }
        red[t] = sum; __syncthreads();
        for (int s = 128; s; s >>= 1) { if (t < s) red[t] += red[t+s]; __syncthreads(); }
        sum = red[0]; __syncthreads();
        red[t] = sq; __syncthreads();
        for (int s = 128; s; s >>= 1) { if (t < s) red[t] += red[t+s]; __syncthreads(); }
        sq = red[0]; __syncthreads();
        float mu = sum / 768.f;
        float var = sq / 768.f - mu*mu;
        float rstd = rsqrtf(var + 1e-5f);
        for (int j = t; j < 768; j += 256)
            out[(size_t)(bg*4+q)*768 + j] = (h2[q*768+j]-mu)*rstd*lng[j] + lnb[j];
    }
}

extern "C" void kernel_launch(void* const* d_in, const int* in_sizes, int n_in,
                              void* d_out, int out_size, void* d_ws, size_t ws_size,
                              hipStream_t stream) {
    const float* x      = (const float*)d_in[0];
    const int*   ids    = (const int*)d_in[1];
    const int*   pad_p  = (const int*)d_in[2];
    const int*   sep_p  = (const int*)d_in[3];
    const float* W_anom = (const float*)d_in[4];
    const float* b_anom = (const float*)d_in[5];
    const float* Wq_sup = (const float*)d_in[6];  const float* bq_sup = (const float*)d_in[7];
    const float* Wk_sup = (const float*)d_in[8];  const float* bk_sup = (const float*)d_in[9];
    const float* Wq_con = (const float*)d_in[10]; const float* bq_con = (const float*)d_in[11];
    const float* Wk_con = (const float*)d_in[12]; const float* bk_con = (const float*)d_in[13];
    const float* Wq_rep = (const float*)d_in[14]; const float* bq_rep = (const float*)d_in[15];
    const float* Wk_rep = (const float*)d_in[16]; const float* bk_rep = (const float*)d_in[17];
    const float* W1     = (const float*)d_in[18]; const float* b1     = (const float*)d_in[19];
    const float* W2     = (const float*)d_in[20]; const float* b2     = (const float*)d_in[21];
    const float* lng    = (const float*)d_in[22]; const float* lnb    = (const float*)d_in[23];
    float* out = (float*)d_out;

    char* w = (char*)d_ws;
    bf16*  xb      = (bf16*)(w);                       // 25,165,824 B
    bf16*  wbT     = (bf16*)(w + 25165824);            //  7,077,888 B
    float* biasAll = (float*)(w + 32243712);           //     18,432 B
    bf16*  qk      = (bf16*)(w + 32262144);            // 150,994,944 B
    float* anom    = (float*)(w + 183257088);          //     65,536 B
    float* gate    = (float*)(w + 183322624);          //     65,536 B
    float* wsup    = (float*)(w + 183388160);          //     65,536 B
    float* wrep    = (float*)(w + 183453696);          //     65,536 B
    float* fused   = (float*)(w + 183519232);          //    294,912 B
    float* h1buf   = (float*)(w + 183814144);          //     98,304 B
    int*   seg     = (int*)  (w + 183912448);          //        256 B

    k_seg<<<B_, 256, 0, stream>>>(ids, pad_p, sep_p, seg);
    k_cast_x<<<4096, 256, 0, stream>>>(x, xb);
    k_cast_w<<<dim3(D_/64, D_/64, 6), 256, 0, stream>>>(Wq_sup, Wk_sup, Wq_con, Wk_con, Wq_rep, Wk_rep, wbT);
    k_bias<<<18, 256, 0, stream>>>(bq_sup, bk_sup, bq_con, bk_con, bq_rep, bk_rep, biasAll);
    k_anom<<<M_/4, 256, 0, stream>>>(x, W_anom, b_anom, anom);
    k_gate<<<B_, 256, 0, stream>>>(anom, ids, seg, pad_p, gate);
    hipMemsetAsync(wsup, 0, 65536*2 + 294912, stream);   // wsup+wrep+fused contiguous
    k_proj<<<dim3(M_/128, 6*D_/128), 256, 0, stream>>>(xb, wbT, biasAll, qk);
    k_score<<<dim3(B_, L_/16), 256, 0, stream>>>(qk, ids, seg, gate, pad_p, wsup, wrep);
    k_fused<<<dim3(B_, 8), 256, 0, stream>>>(x, gate, wrep, wsup, fused);
    k_mlp1<<<dim3(8, 3), 256, 0, stream>>>(fused, W1, b1, h1buf);
    k_mlp2<<<8, 256, 0, stream>>>(h1buf, W2, b2, lng, lnb, out);
}

// Round 4
// 490.935 us; speedup vs baseline: 3.4617x; 1.5636x over previous
//
#include <hip/hip_runtime.h>
#include <hip/hip_bf16.h>

#define B_ 32
#define L_ 512
#define D_ 768
#define M_ (B_*L_)
#define NEGV (-9e15f)

typedef __hip_bfloat16 bf16;
typedef short v8s __attribute__((ext_vector_type(8)));
typedef float v4f __attribute__((ext_vector_type(4)));

static __device__ __forceinline__ unsigned short f2b(float f) {
    __hip_bfloat16 h = __float2bfloat16(f);
    return *reinterpret_cast<unsigned short*>(&h);
}

static __device__ __forceinline__ float fast_tanh(float x) {
    x = fminf(fmaxf(x, -15.f), 15.f);
    float e2 = __expf(2.f * x);
    return (e2 - 1.f) / (e2 + 1.f);
}

// async global->LDS, 16B per lane; lds dest is wave-uniform base, HW scatters lane i at base+i*16
static __device__ __forceinline__ void gl_lds16(const void* g, void* l) {
    __builtin_amdgcn_global_load_lds(
        (const __attribute__((address_space(1))) unsigned int*)g,
        (__attribute__((address_space(3))) unsigned int*)l, 16, 0, 0);
}

// ---------------- segment info: sep_pos, valid_len per batch ----------------
__global__ void k_seg(const int* ids, const int* pad_p, const int* sep_p, int* seg) {
    int b = blockIdx.x, t = threadIdx.x;
    __shared__ int red[256];
    int pad = *pad_p, sepid = *sep_p;
    int minsep = L_, vcount = 0;
    for (int l = t; l < L_; l += 256) {
        int id = ids[b*L_ + l];
        if (id == sepid && l < minsep) minsep = l;
        if (id != pad) vcount++;
    }
    red[t] = minsep; __syncthreads();
    for (int s = 128; s > 0; s >>= 1) { if (t < s) red[t] = min(red[t], red[t+s]); __syncthreads(); }
    int sepmin = red[0]; __syncthreads();
    red[t] = vcount; __syncthreads();
    for (int s = 128; s > 0; s >>= 1) { if (t < s) red[t] += red[t+s]; __syncthreads(); }
    if (t == 0) {
        int vlen = red[0];
        int fb = vlen / 2; if (fb < 1) fb = 1; if (fb > L_-2) fb = L_-2;
        int sep = (sepmin < L_) ? sepmin : fb;
        seg[b*2] = sep; seg[b*2+1] = vlen;
    }
}

// ---------------- cast x to bf16 ----------------
__global__ void k_cast_x(const float* __restrict__ x, bf16* __restrict__ xb) {
    int n4 = M_*D_/4;
    for (int i = blockIdx.x*blockDim.x + threadIdx.x; i < n4; i += gridDim.x*blockDim.x) {
        float4 v = reinterpret_cast<const float4*>(x)[i];
        ushort4 o;
        o.x = f2b(v.x); o.y = f2b(v.y); o.z = f2b(v.z); o.w = f2b(v.w);
        reinterpret_cast<ushort4*>(xb)[i] = o;
    }
}

// ------- cast+transpose 6 weights to bf16 [n][k], LDS-tiled -------
__global__ __launch_bounds__(256) void k_cast_w(const float* w0, const float* w1, const float* w2,
                         const float* w3, const float* w4, const float* w5,
                         bf16* __restrict__ wbT) {
    int widx = blockIdx.z;
    const float* W;
    switch (widx) { case 0: W=w0; break; case 1: W=w1; break; case 2: W=w2; break;
                    case 3: W=w3; break; case 4: W=w4; break; default: W=w5; }
    __shared__ float tile[64][65];
    int t = threadIdx.x;
    int tr = t >> 6, tc = t & 63;
    int n0 = blockIdx.x*64, k0 = blockIdx.y*64;
    #pragma unroll
    for (int i = tr; i < 64; i += 4)
        tile[i][tc] = W[(size_t)(k0+i)*D_ + n0 + tc];
    __syncthreads();
    bf16* dst = wbT + (size_t)widx*D_*D_;
    #pragma unroll
    for (int i = tr; i < 64; i += 4)
        dst[(size_t)(n0+i)*D_ + k0 + tc] = __float2bfloat16(tile[tc][i]);
}

__global__ void k_bias(const float* b0, const float* b1, const float* b2,
                       const float* b3, const float* b4, const float* b5,
                       float* biasAll) {
    int t = blockIdx.x*256 + threadIdx.x;
    if (t >= 6*D_) return;
    int w = t / D_, j = t % D_;
    const float* p;
    switch (w) { case 0: p=b0; break; case 1: p=b1; break; case 2: p=b2; break;
                 case 3: p=b3; break; case 4: p=b4; break; default: p=b5; }
    biasAll[t] = p[j];
}

// ---------------- anomaly logits: one wave per row ----------------
__global__ void k_anom(const float* __restrict__ x, const float* __restrict__ Wa,
                       const float* __restrict__ ba, float* __restrict__ anom) {
    int gw = (blockIdx.x*blockDim.x + threadIdx.x) >> 6;
    int lane = threadIdx.x & 63;
    if (gw >= M_) return;
    const float* xr = x + (size_t)gw*D_;
    float s = 0.f;
    #pragma unroll
    for (int i = 0; i < D_/64; i++) s += xr[lane + 64*i] * Wa[lane + 64*i];
    #pragma unroll
    for (int m = 32; m; m >>= 1) s += __shfl_xor(s, m);
    if (lane == 0) anom[gw] = s + ba[0];
}

// ---------------- gate: masked softmax over false segment ----------------
__global__ void k_gate(const float* __restrict__ anom, const int* __restrict__ ids,
                       const int* seg, const int* pad_p, float* __restrict__ gate) {
    int b = blockIdx.x, t = threadIdx.x;
    int sep = seg[b*2]; int pad = *pad_p;
    __shared__ float red[256];
    float a0[2]; bool f0[2];
    float mx = -__builtin_inff();
    #pragma unroll
    for (int j = 0; j < 2; j++) {
        int l = t + j*256;
        bool fm = (l < sep) && (ids[b*L_+l] != pad);
        float a = anom[b*L_+l];
        f0[j] = fm; a0[j] = a;
        if (fm) mx = fmaxf(mx, a);
    }
    red[t] = mx; __syncthreads();
    for (int s = 128; s; s >>= 1) { if (t < s) red[t] = fmaxf(red[t], red[t+s]); __syncthreads(); }
    mx = red[0]; __syncthreads();
    float e[2]; float se = 0.f;
    #pragma unroll
    for (int j = 0; j < 2; j++) { e[j] = f0[j] ? __expf(a0[j]-mx) : 0.f; se += e[j]; }
    red[t] = se; __syncthreads();
    for (int s = 128; s; s >>= 1) { if (t < s) red[t] += red[t+s]; __syncthreads(); }
    se = red[0];
    float inv = 1.f / fmaxf(se, 1e-8f);
    #pragma unroll
    for (int j = 0; j < 2; j++) { int l = t + j*256; gate[b*L_+l] = e[j]*inv; }
}

// -------- fused projections as one GEMM: [16384 x 4608] = xb @ wbTall^T ----
__global__ __launch_bounds__(256) void k_proj(const bf16* __restrict__ xb,
                                              const bf16* __restrict__ wbT,
                                              const float* __restrict__ biasAll,
                                              bf16* __restrict__ qk) {
    __shared__ bf16 As[128*32];
    __shared__ bf16 Bs[128*32];
    int t = threadIdx.x;
    int wave = t >> 6, lane = t & 63;
    int quad = lane >> 4, l16 = lane & 15;
    int wm = wave >> 1, wn = wave & 1;
    int row0 = blockIdx.x * 128;
    int gn0  = blockIdx.y * 128;

    v4f acc[4][4];
    #pragma unroll
    for (int i = 0; i < 4; i++)
        #pragma unroll
        for (int j = 0; j < 4; j++) acc[i][j] = (v4f){0.f,0.f,0.f,0.f};

    int srow = lane >> 2;
    int skoff = (lane & 3) * 8;
    const bf16* agp0 = xb  + (size_t)(row0 + wave*32 + srow)*D_ + skoff;
    const bf16* agp1 = agp0 + 16*D_;
    const bf16* bgp0 = wbT + (size_t)(gn0 + wave*32 + srow)*D_ + skoff;
    const bf16* bgp1 = bgp0 + 16*D_;
    bf16* al0 = &As[(wave*2    )*512];
    bf16* al1 = &As[(wave*2 + 1)*512];
    bf16* bl0 = &Bs[(wave*2    )*512];
    bf16* bl1 = &Bs[(wave*2 + 1)*512];

    for (int k0 = 0; k0 < D_; k0 += 32) {
        gl_lds16(agp0 + k0, al0);
        gl_lds16(agp1 + k0, al1);
        gl_lds16(bgp0 + k0, bl0);
        gl_lds16(bgp1 + k0, bl1);
        __syncthreads();
        v8s af[4], bf[4];
        #pragma unroll
        for (int i = 0; i < 4; i++)
            af[i] = *reinterpret_cast<const v8s*>(&As[(wm*64 + i*16 + l16)*32 + quad*8]);
        #pragma unroll
        for (int j = 0; j < 4; j++)
            bf[j] = *reinterpret_cast<const v8s*>(&Bs[(wn*64 + j*16 + l16)*32 + quad*8]);
        #pragma unroll
        for (int i = 0; i < 4; i++)
            #pragma unroll
            for (int j = 0; j < 4; j++)
                acc[i][j] = __builtin_amdgcn_mfma_f32_16x16x32_bf16(af[i], bf[j], acc[i][j], 0, 0, 0);
        __syncthreads();
    }

    int widx = blockIdx.y / 6;
    int nw0  = (blockIdx.y % 6) * 128;
    bf16* out = qk + (size_t)widx*M_*D_;
    float bias[4];
    #pragma unroll
    for (int j = 0; j < 4; j++) bias[j] = biasAll[gn0 + wn*64 + j*16 + l16];
    #pragma unroll
    for (int i = 0; i < 4; i++) {
        #pragma unroll
        for (int j = 0; j < 4; j++) {
            int n = nw0 + wn*64 + j*16 + l16;
            #pragma unroll
            for (int r = 0; r < 4; r++) {
                int m = row0 + wm*64 + i*16 + quad*4 + r;
                out[(size_t)m*D_ + n] = __float2bfloat16(acc[i][j][r] + bias[j]);
            }
        }
    }
}

// ------ scores in registers: per-wave 6 col-tiles, softmax + gate-reduce ----
__global__ __launch_bounds__(256) void k_score(const bf16* __restrict__ qk,
                                               const int* __restrict__ ids,
                                               const int* __restrict__ seg,
                                               const float* __restrict__ gate,
                                               const int* pad_p,
                                               float* __restrict__ w_sup,
                                               float* __restrict__ w_rep) {
    int b = blockIdx.x, rt = blockIdx.y;          // x=batch for XCD L2 affinity
    int sep = seg[b*2];
    int r0 = rt*16;
    if (r0 >= sep) return;
    int pad = *pad_p;
    int wave = threadIdx.x >> 6, lane = threadIdx.x & 63;
    int quad = lane >> 4, l16 = lane & 15;
    const float inv  = 0.03608439182435161f;      // 1/sqrt(768)
    const float rinv = 27.712812921102035f;       // sqrt(768)
    int ct0 = (sep + 1) >> 4;                     // first tile containing cols > sep

    int tile[6]; bool act[6];
    #pragma unroll
    for (int i = 0; i < 6; i++) {
        int ctv = ct0 + wave + 4*i;
        act[i] = ctv < 32;
        tile[i] = act[i] ? ctv : 31;
    }
    int qoff = (r0 + l16)*D_ + quad*8;
    int koff[6];
    #pragma unroll
    for (int i = 0; i < 6; i++) koff[i] = (tile[i]*16 + l16)*D_ + quad*8;

    v4f S[6], R[6];
    #pragma unroll
    for (int i = 0; i < 6; i++) { S[i] = (v4f){0,0,0,0}; R[i] = (v4f){0,0,0,0}; }

    const size_t bo = (size_t)b*L_*D_;
    // --- head con (slots 2,3) into R ---
    {
        const bf16* Q = qk + (size_t)2*M_*D_ + bo;
        const bf16* K = qk + (size_t)3*M_*D_ + bo;
        for (int k0 = 0; k0 < D_; k0 += 32) {
            v8s a = *reinterpret_cast<const v8s*>(Q + qoff + k0);
            #pragma unroll
            for (int i = 0; i < 6; i++) {
                v8s kf = *reinterpret_cast<const v8s*>(K + koff[i] + k0);
                R[i] = __builtin_amdgcn_mfma_f32_16x16x32_bf16(a, kf, R[i], 0, 0, 0);
            }
        }
    }
    // R := tanh(con*inv)/inv  so that after adding rep_raw, R*inv = rep*inv + tanh
    #pragma unroll
    for (int i = 0; i < 6; i++)
        #pragma unroll
        for (int r = 0; r < 4; r++)
            R[i][r] = fast_tanh(R[i][r]*inv) * rinv;
    // --- head rep (slots 4,5) accumulates into R ---
    {
        const bf16* Q = qk + (size_t)4*M_*D_ + bo;
        const bf16* K = qk + (size_t)5*M_*D_ + bo;
        for (int k0 = 0; k0 < D_; k0 += 32) {
            v8s a = *reinterpret_cast<const v8s*>(Q + qoff + k0);
            #pragma unroll
            for (int i = 0; i < 6; i++) {
                v8s kf = *reinterpret_cast<const v8s*>(K + koff[i] + k0);
                R[i] = __builtin_amdgcn_mfma_f32_16x16x32_bf16(a, kf, R[i], 0, 0, 0);
            }
        }
    }
    // --- head sup (slots 0,1) into S ---
    {
        const bf16* Q = qk + bo;
        const bf16* K = qk + (size_t)M_*D_ + bo;
        for (int k0 = 0; k0 < D_; k0 += 32) {
            v8s a = *reinterpret_cast<const v8s*>(Q + qoff + k0);
            #pragma unroll
            for (int i = 0; i < 6; i++) {
                v8s kf = *reinterpret_cast<const v8s*>(K + koff[i] + k0);
                S[i] = __builtin_amdgcn_mfma_f32_16x16x32_bf16(a, kf, S[i], 0, 0, 0);
            }
        }
    }

    bool opt[6];
    #pragma unroll
    for (int i = 0; i < 6; i++) {
        int c = tile[i]*16 + l16;
        opt[i] = act[i] && (c > sep) && (ids[b*L_ + c] != pad);
    }

    float mxs[4], mxr[4];
    #pragma unroll
    for (int r = 0; r < 4; r++) { mxs[r] = NEGV; mxr[r] = NEGV; }
    #pragma unroll
    for (int i = 0; i < 6; i++)
        #pragma unroll
        for (int r = 0; r < 4; r++) {
            float sv = opt[i] ? S[i][r]*inv : NEGV;
            float rv = opt[i] ? R[i][r]*inv : NEGV;
            mxs[r] = fmaxf(mxs[r], sv);
            mxr[r] = fmaxf(mxr[r], rv);
        }
    #pragma unroll
    for (int d = 1; d < 16; d <<= 1)
        #pragma unroll
        for (int r = 0; r < 4; r++) {
            mxs[r] = fmaxf(mxs[r], __shfl_xor(mxs[r], d));
            mxr[r] = fmaxf(mxr[r], __shfl_xor(mxr[r], d));
        }
    __shared__ float redm[2][16][4];
    __shared__ float reds[2][16][4];
    if (l16 == 0)
        #pragma unroll
        for (int r = 0; r < 4; r++) {
            redm[0][quad*4+r][wave] = mxs[r];
            redm[1][quad*4+r][wave] = mxr[r];
        }
    __syncthreads();
    #pragma unroll
    for (int r = 0; r < 4; r++) {
        int row = quad*4 + r;
        mxs[r] = fmaxf(fmaxf(redm[0][row][0], redm[0][row][1]), fmaxf(redm[0][row][2], redm[0][row][3]));
        mxr[r] = fmaxf(fmaxf(redm[1][row][0], redm[1][row][1]), fmaxf(redm[1][row][2], redm[1][row][3]));
    }

    float ssum[4] = {0,0,0,0}, rsum[4] = {0,0,0,0};
    #pragma unroll
    for (int i = 0; i < 6; i++)
        #pragma unroll
        for (int r = 0; r < 4; r++) {
            float es = opt[i] ? __expf(S[i][r]*inv - mxs[r]) : 0.f;
            float er = opt[i] ? __expf(R[i][r]*inv - mxr[r]) : 0.f;
            S[i][r] = es; R[i][r] = er;
            ssum[r] += es; rsum[r] += er;
        }
    #pragma unroll
    for (int d = 1; d < 16; d <<= 1)
        #pragma unroll
        for (int r = 0; r < 4; r++) {
            ssum[r] += __shfl_xor(ssum[r], d);
            rsum[r] += __shfl_xor(rsum[r], d);
        }
    if (l16 == 0)
        #pragma unroll
        for (int r = 0; r < 4; r++) {
            reds[0][quad*4+r][wave] = ssum[r];
            reds[1][quad*4+r][wave] = rsum[r];
        }
    __syncthreads();
    float gs_[4], gr_[4];
    #pragma unroll
    for (int r = 0; r < 4; r++) {
        int row = quad*4 + r;
        float st = reds[0][row][0] + reds[0][row][1] + reds[0][row][2] + reds[0][row][3];
        float rtot = reds[1][row][0] + reds[1][row][1] + reds[1][row][2] + reds[1][row][3];
        float g = gate[b*L_ + r0 + row];
        gs_[r] = g / st;
        gr_[r] = g / rtot;
    }

    #pragma unroll
    for (int i = 0; i < 6; i++) {
        float cs = 0.f, cr = 0.f;
        #pragma unroll
        for (int r = 0; r < 4; r++) { cs += S[i][r]*gs_[r]; cr += R[i][r]*gr_[r]; }
        cs += __shfl_xor(cs, 16); cs += __shfl_xor(cs, 32);
        cr += __shfl_xor(cr, 16); cr += __shfl_xor(cr, 32);
        if (act[i] && quad == 0) {
            int c = tile[i]*16 + l16;
            atomicAdd(&w_sup[b*L_ + c], cs);
            atomicAdd(&w_rep[b*L_ + c], cr);
        }
    }
}

// ---- 3 gemvs over L: partial per 64-row chunk, atomic into fused[32][2304] --
__global__ __launch_bounds__(256) void k_fused(const float* __restrict__ x,
                                               const float* __restrict__ gate,
                                               const float* __restrict__ wrep,
                                               const float* __restrict__ wsup,
                                               float* __restrict__ fused) {
    int b = blockIdx.x, ch = blockIdx.y, t = threadIdx.x;
    int l0 = ch*64;
    const float* xb_ = x + (size_t)b*L_*D_;
    float a0=0,a1=0,a2=0, r0=0,r1=0,r2=0, s0=0,s1=0,s2=0;
    for (int l = l0; l < l0+64; l++) {
        float g = gate[b*L_+l], wr = wrep[b*L_+l], wv = wsup[b*L_+l];
        if (g == 0.f && wr == 0.f && wv == 0.f) continue;
        float x0 = xb_[l*D_ + t], x1 = xb_[l*D_ + t + 256], x2 = xb_[l*D_ + t + 512];
        a0 += g*x0;  a1 += g*x1;  a2 += g*x2;
        r0 += wr*x0; r1 += wr*x1; r2 += wr*x2;
        s0 += wv*x0; s1 += wv*x1; s2 += wv*x2;
    }
    float* f = fused + (size_t)b*2304;
    atomicAdd(&f[t],        a0); atomicAdd(&f[t+256],      a1); atomicAdd(&f[t+512],      a2);
    atomicAdd(&f[768+t],    r0); atomicAdd(&f[768+t+256],  r1); atomicAdd(&f[768+t+512],  r2);
    atomicAdd(&f[1536+t],   s0); atomicAdd(&f[1536+t+256], s1); atomicAdd(&f[1536+t+512], s2);
}

// ---- MLP layer 1, split-K: 216 blocks, partial sums into h1pre via atomics ----
__global__ __launch_bounds__(256) void k_mlp1(const float* __restrict__ fused,
                                              const float* __restrict__ W1,
                                              float* __restrict__ h1pre) {
    int c0 = blockIdx.x*64, k0 = blockIdx.y*128;
    int t = threadIdx.x;
    __shared__ float fsl[32][132];
    for (int i = t*4; i < 32*128; i += 1024) {
        int b = i >> 7, k = i & 127;
        const float4 v = *reinterpret_cast<const float4*>(&fused[(size_t)b*2304 + k0 + k]);
        fsl[b][k] = v.x; fsl[b][k+1] = v.y; fsl[b][k+2] = v.z; fsl[b][k+3] = v.w;
    }
    __syncthreads();
    int c = c0 + (t & 63), bg = (t >> 6) * 8;
    float acc[8] = {0,0,0,0,0,0,0,0};
    for (int k = 0; k < 128; k++) {
        float w = W1[(size_t)(k0+k)*D_ + c];
        #pragma unroll
        for (int b = 0; b < 8; b++) acc[b] += fsl[bg+b][k] * w;
    }
    #pragma unroll
    for (int b = 0; b < 8; b++) atomicAdd(&h1pre[(size_t)(bg+b)*D_ + c], acc[b]);
}

// ---- MLP layer 2, split-K: relu(h1pre+b1) on load; partials into opre ----
__global__ __launch_bounds__(256) void k_mlp2(const float* __restrict__ h1pre,
                                              const float* __restrict__ b1,
                                              const float* __restrict__ W2,
                                              float* __restrict__ opre) {
    int c0 = blockIdx.x*64, k0 = blockIdx.y*128;
    int t = threadIdx.x;
    __shared__ float fsl[32][132];
    for (int i = t*4; i < 32*128; i += 1024) {
        int b = i >> 7, k = i & 127;
        const float4 v = *reinterpret_cast<const float4*>(&h1pre[(size_t)b*D_ + k0 + k]);
        const float4 bb = *reinterpret_cast<const float4*>(&b1[k0 + k]);
        fsl[b][k]   = fmaxf(v.x + bb.x, 0.f);
        fsl[b][k+1] = fmaxf(v.y + bb.y, 0.f);
        fsl[b][k+2] = fmaxf(v.z + bb.z, 0.f);
        fsl[b][k+3] = fmaxf(v.w + bb.w, 0.f);
    }
    __syncthreads();
    int c = c0 + (t & 63), bg = (t >> 6) * 8;
    float acc[8] = {0,0,0,0,0,0,0,0};
    for (int k = 0; k < 128; k++) {
        float w = W2[(size_t)(k0+k)*D_ + c];
        #pragma unroll
        for (int b = 0; b < 8; b++) acc[b] += fsl[bg+b][k] * w;
    }
    #pragma unroll
    for (int b = 0; b < 8; b++) atomicAdd(&opre[(size_t)(bg+b)*D_ + c], acc[b]);
}

// ---- bias2 + LayerNorm: one block per batch ----
__global__ __launch_bounds__(256) void k_ln(const float* __restrict__ opre,
                                            const float* __restrict__ b2,
                                            const float* __restrict__ lng,
                                            const float* __restrict__ lnb,
                                            float* __restrict__ out) {
    int b = blockIdx.x, t = threadIdx.x;
    __shared__ float red[256];
    float v0 = opre[(size_t)b*D_ + t]       + b2[t];
    float v1 = opre[(size_t)b*D_ + t + 256] + b2[t+256];
    float v2 = opre[(size_t)b*D_ + t + 512] + b2[t+512];
    float sum = v0+v1+v2, sq = v0*v0+v1*v1+v2*v2;
    red[t] = sum; __syncthreads();
    for (int s = 128; s; s >>= 1) { if (t < s) red[t] += red[t+s]; __syncthreads(); }
    sum = red[0]; __syncthreads();
    red[t] = sq; __syncthreads();
    for (int s = 128; s; s >>= 1) { if (t < s) red[t] += red[t+s]; __syncthreads(); }
    sq = red[0];
    float mu = sum / 768.f;
    float var = sq / 768.f - mu*mu;
    float rstd = rsqrtf(var + 1e-5f);
    out[(size_t)b*D_ + t]       = (v0-mu)*rstd*lng[t]     + lnb[t];
    out[(size_t)b*D_ + t + 256] = (v1-mu)*rstd*lng[t+256] + lnb[t+256];
    out[(size_t)b*D_ + t + 512] = (v2-mu)*rstd*lng[t+512] + lnb[t+512];
}

extern "C" void kernel_launch(void* const* d_in, const int* in_sizes, int n_in,
                              void* d_out, int out_size, void* d_ws, size_t ws_size,
                              hipStream_t stream) {
    const float* x      = (const float*)d_in[0];
    const int*   ids    = (const int*)d_in[1];
    const int*   pad_p  = (const int*)d_in[2];
    const int*   sep_p  = (const int*)d_in[3];
    const float* W_anom = (const float*)d_in[4];
    const float* b_anom = (const float*)d_in[5];
    const float* Wq_sup = (const float*)d_in[6];  const float* bq_sup = (const float*)d_in[7];
    const float* Wk_sup = (const float*)d_in[8];  const float* bk_sup = (const float*)d_in[9];
    const float* Wq_con = (const float*)d_in[10]; const float* bq_con = (const float*)d_in[11];
    const float* Wk_con = (const float*)d_in[12]; const float* bk_con = (const float*)d_in[13];
    const float* Wq_rep = (const float*)d_in[14]; const float* bq_rep = (const float*)d_in[15];
    const float* Wk_rep = (const float*)d_in[16]; const float* bk_rep = (const float*)d_in[17];
    const float* W1     = (const float*)d_in[18]; const float* b1     = (const float*)d_in[19];
    const float* W2     = (const float*)d_in[20]; const float* b2     = (const float*)d_in[21];
    const float* lng    = (const float*)d_in[22]; const float* lnb    = (const float*)d_in[23];
    float* out = (float*)d_out;

    char* w = (char*)d_ws;
    bf16*  xb      = (bf16*)(w);                       // 25,165,824 B
    bf16*  wbT     = (bf16*)(w + 25165824);            //  7,077,888 B
    float* biasAll = (float*)(w + 32243712);           //     18,432 B
    bf16*  qk      = (bf16*)(w + 32262144);            // 150,994,944 B
    float* anom    = (float*)(w + 183257088);          //     65,536 B
    float* gate    = (float*)(w + 183322624);          //     65,536 B
    float* wsup    = (float*)(w + 183388160);          //     65,536 B
    float* wrep    = (float*)(w + 183453696);          //     65,536 B
    float* fused   = (float*)(w + 183519232);          //    294,912 B
    float* h1pre   = (float*)(w + 183814144);          //     98,304 B
    float* opre    = (float*)(w + 183912448);          //     98,304 B
    int*   seg     = (int*)  (w + 184010752);          //        256 B

    k_seg<<<B_, 256, 0, stream>>>(ids, pad_p, sep_p, seg);
    k_cast_x<<<4096, 256, 0, stream>>>(x, xb);
    k_cast_w<<<dim3(D_/64, D_/64, 6), 256, 0, stream>>>(Wq_sup, Wk_sup, Wq_con, Wk_con, Wq_rep, Wk_rep, wbT);
    k_bias<<<18, 256, 0, stream>>>(bq_sup, bk_sup, bq_con, bk_con, bq_rep, bk_rep, biasAll);
    k_anom<<<M_/4, 256, 0, stream>>>(x, W_anom, b_anom, anom);
    k_gate<<<B_, 256, 0, stream>>>(anom, ids, seg, pad_p, gate);
    // zero: wsup + wrep + fused + h1pre + opre (contiguous, 622,592 B)
    hipMemsetAsync(wsup, 0, 622592, stream);
    k_proj<<<dim3(M_/128, 6*D_/128), 256, 0, stream>>>(xb, wbT, biasAll, qk);
    k_score<<<dim3(B_, L_/16), 256, 0, stream>>>(qk, ids, seg, gate, pad_p, wsup, wrep);
    k_fused<<<dim3(B_, 8), 256, 0, stream>>>(x, gate, wrep, wsup, fused);
    k_mlp1<<<dim3(12, 18), 256, 0, stream>>>(fused, W1, h1pre);
    k_mlp2<<<dim3(12, 6), 256, 0, stream>>>(h1pre, b1, W2, opre);
    k_ln<<<B_, 256, 0, stream>>>(opre, b2, lng, lnb, out);
}

// Round 5
// 357.879 us; speedup vs baseline: 4.7487x; 1.3718x over previous
//
#include <hip/hip_runtime.h>
#include <hip/hip_bf16.h>

#define B_ 32
#define L_ 512
#define D_ 768
#define M_ (B_*L_)
#define NEGV (-9e15f)

typedef __hip_bfloat16 bf16;
typedef short v8s __attribute__((ext_vector_type(8)));
typedef float v4f __attribute__((ext_vector_type(4)));

static __device__ __forceinline__ unsigned short f2b(float f) {
    __hip_bfloat16 h = __float2bfloat16(f);
    return *reinterpret_cast<unsigned short*>(&h);
}

static __device__ __forceinline__ float fast_tanh(float x) {
    x = fminf(fmaxf(x, -15.f), 15.f);
    float e2 = __expf(2.f * x);
    return (e2 - 1.f) / (e2 + 1.f);
}

// async global->LDS, 16B per lane; lds dest is wave-uniform base, HW scatters lane i at base+i*16
static __device__ __forceinline__ void gl_lds16(const void* g, void* l) {
    __builtin_amdgcn_global_load_lds(
        (const __attribute__((address_space(1))) unsigned int*)g,
        (__attribute__((address_space(3))) unsigned int*)l, 16, 0, 0);
}

// ---------------- segment info: sep_pos, valid_len per batch ----------------
__global__ void k_seg(const int* ids, const int* pad_p, const int* sep_p, int* seg) {
    int b = blockIdx.x, t = threadIdx.x;
    __shared__ int red[256];
    int pad = *pad_p, sepid = *sep_p;
    int minsep = L_, vcount = 0;
    for (int l = t; l < L_; l += 256) {
        int id = ids[b*L_ + l];
        if (id == sepid && l < minsep) minsep = l;
        if (id != pad) vcount++;
    }
    red[t] = minsep; __syncthreads();
    for (int s = 128; s > 0; s >>= 1) { if (t < s) red[t] = min(red[t], red[t+s]); __syncthreads(); }
    int sepmin = red[0]; __syncthreads();
    red[t] = vcount; __syncthreads();
    for (int s = 128; s > 0; s >>= 1) { if (t < s) red[t] += red[t+s]; __syncthreads(); }
    if (t == 0) {
        int vlen = red[0];
        int fb = vlen / 2; if (fb < 1) fb = 1; if (fb > L_-2) fb = L_-2;
        int sep = (sepmin < L_) ? sepmin : fb;
        seg[b*2] = sep; seg[b*2+1] = vlen;
    }
}

// ---------------- cast x to bf16 ----------------
__global__ void k_cast_x(const float* __restrict__ x, bf16* __restrict__ xb) {
    int n4 = M_*D_/4;
    for (int i = blockIdx.x*blockDim.x + threadIdx.x; i < n4; i += gridDim.x*blockDim.x) {
        float4 v = reinterpret_cast<const float4*>(x)[i];
        ushort4 o;
        o.x = f2b(v.x); o.y = f2b(v.y); o.z = f2b(v.z); o.w = f2b(v.w);
        reinterpret_cast<ushort4*>(xb)[i] = o;
    }
}

// ------- plain cast of 6 weights to bf16 (row-major, no transpose) -------
__global__ __launch_bounds__(256) void k_castw6(const float* w0, const float* w1, const float* w2,
                         const float* w3, const float* w4, const float* w5,
                         bf16* __restrict__ wb6) {
    int widx = blockIdx.y;
    const float* W;
    switch (widx) { case 0: W=w0; break; case 1: W=w1; break; case 2: W=w2; break;
                    case 3: W=w3; break; case 4: W=w4; break; default: W=w5; }
    int o = blockIdx.x*256 + threadIdx.x;
    wb6[(size_t)widx*D_*D_ + o] = __float2bfloat16(W[o]);
}

// ---- bias-fold vectors: vc_h = Wk_h @ bq_h (h=sup,con,rep), u_con = Wq_con @ bk_con,
// ---- d_con = bq_con . bk_con.  One wave per output element.
__global__ void k_vecs(const float* Wk_sup, const float* bq_sup,
                       const float* Wk_con, const float* bq_con,
                       const float* Wk_rep, const float* bq_rep,
                       const float* Wq_con, const float* bk_con,
                       float* __restrict__ vecs) {
    int gw = (blockIdx.x*blockDim.x + threadIdx.x) >> 6;
    int lane = threadIdx.x & 63;
    if (gw > 3072) return;
    if (gw == 3072) {   // d_con
        float s = 0.f;
        #pragma unroll
        for (int i = 0; i < D_/64; i++) s += bq_con[lane + 64*i] * bk_con[lane + 64*i];
        #pragma unroll
        for (int m = 32; m; m >>= 1) s += __shfl_xor(s, m);
        if (lane == 0) vecs[3072] = s;
        return;
    }
    int sel = gw / D_, row = gw % D_;
    const float* Wrow; const float* bv;
    switch (sel) {
        case 0: Wrow = Wk_sup + (size_t)row*D_; bv = bq_sup; break;
        case 1: Wrow = Wk_con + (size_t)row*D_; bv = bq_con; break;
        case 2: Wrow = Wk_rep + (size_t)row*D_; bv = bq_rep; break;
        default: Wrow = Wq_con + (size_t)row*D_; bv = bk_con; break;
    }
    float s = 0.f;
    #pragma unroll
    for (int i = 0; i < D_/64; i++) s += Wrow[lane + 64*i] * bv[lane + 64*i];
    #pragma unroll
    for (int m = 32; m; m >>= 1) s += __shfl_xor(s, m);
    if (lane == 0) vecs[gw] = s;
}

// ---- per-row dots: anom, c_sup, c_con, c_rep, r_con — one x-row read, 5 dots ----
__global__ void k_rowdots(const float* __restrict__ x, const float* __restrict__ Wa,
                          const float* __restrict__ ba, const float* __restrict__ vecs,
                          float* __restrict__ anom, float* __restrict__ csup,
                          float* __restrict__ ccon, float* __restrict__ crep,
                          float* __restrict__ rcon) {
    int gw = (blockIdx.x*blockDim.x + threadIdx.x) >> 6;
    int lane = threadIdx.x & 63;
    if (gw >= M_) return;
    const float* xr = x + (size_t)gw*D_;
    float sa=0.f, s0=0.f, s1=0.f, s2=0.f, s3=0.f;
    #pragma unroll
    for (int i = 0; i < D_/64; i++) {
        int o = lane + 64*i;
        float xv = xr[o];
        sa += xv * Wa[o];
        s0 += xv * vecs[o];
        s1 += xv * vecs[768 + o];
        s2 += xv * vecs[1536 + o];
        s3 += xv * vecs[2304 + o];
    }
    #pragma unroll
    for (int m = 32; m; m >>= 1) {
        sa += __shfl_xor(sa, m); s0 += __shfl_xor(s0, m); s1 += __shfl_xor(s1, m);
        s2 += __shfl_xor(s2, m); s3 += __shfl_xor(s3, m);
    }
    if (lane == 0) {
        anom[gw] = sa + ba[0];
        csup[gw] = s0; ccon[gw] = s1; crep[gw] = s2; rcon[gw] = s3;
    }
}

// ---------------- gate: masked softmax over false segment ----------------
__global__ void k_gate(const float* __restrict__ anom, const int* __restrict__ ids,
                       const int* seg, const int* pad_p, float* __restrict__ gate) {
    int b = blockIdx.x, t = threadIdx.x;
    int sep = seg[b*2]; int pad = *pad_p;
    __shared__ float red[256];
    float a0[2]; bool f0[2];
    float mx = -__builtin_inff();
    #pragma unroll
    for (int j = 0; j < 2; j++) {
        int l = t + j*256;
        bool fm = (l < sep) && (ids[b*L_+l] != pad);
        float a = anom[b*L_+l];
        f0[j] = fm; a0[j] = a;
        if (fm) mx = fmaxf(mx, a);
    }
    red[t] = mx; __syncthreads();
    for (int s = 128; s; s >>= 1) { if (t < s) red[t] = fmaxf(red[t], red[t+s]); __syncthreads(); }
    mx = red[0]; __syncthreads();
    float e[2]; float se = 0.f;
    #pragma unroll
    for (int j = 0; j < 2; j++) { e[j] = f0[j] ? __expf(a0[j]-mx) : 0.f; se += e[j]; }
    red[t] = se; __syncthreads();
    for (int s = 128; s; s >>= 1) { if (t < s) red[t] += red[t+s]; __syncthreads(); }
    se = red[0];
    float inv = 1.f / fmaxf(se, 1e-8f);
    #pragma unroll
    for (int j = 0; j < 2; j++) { int l = t + j*256; gate[b*L_+l] = e[j]*inv; }
}

// ---- AT_h = Wk_h @ Wq_h^T  (AT[v][u] = sum_i Wk[v][i] Wq[u][i] = A[u][v]) ----
// m97 structure, 128x128 tile, K=768.
__global__ __launch_bounds__(256) void k_wqk(const bf16* __restrict__ wb6,
                                             bf16* __restrict__ AT) {
    int h = blockIdx.z;
    const bf16* Asrc = wb6 + (size_t)(2*h+1)*D_*D_;   // Wk rows
    const bf16* Bsrc = wb6 + (size_t)(2*h)*D_*D_;     // Wq rows
    bf16* outp = AT + (size_t)h*D_*D_;
    __shared__ bf16 As[128*32];
    __shared__ bf16 Bs[128*32];
    int t = threadIdx.x;
    int wave = t >> 6, lane = t & 63;
    int quad = lane >> 4, l16 = lane & 15;
    int wm = wave >> 1, wn = wave & 1;
    int row0 = blockIdx.x * 128;
    int col0 = blockIdx.y * 128;

    v4f acc[4][4];
    #pragma unroll
    for (int i = 0; i < 4; i++)
        #pragma unroll
        for (int j = 0; j < 4; j++) acc[i][j] = (v4f){0.f,0.f,0.f,0.f};

    int srow = lane >> 2;
    int skoff = (lane & 3) * 8;
    const bf16* agp0 = Asrc + (size_t)(row0 + wave*32 + srow)*D_ + skoff;
    const bf16* agp1 = agp0 + 16*D_;
    const bf16* bgp0 = Bsrc + (size_t)(col0 + wave*32 + srow)*D_ + skoff;
    const bf16* bgp1 = bgp0 + 16*D_;
    bf16* al0 = &As[(wave*2    )*512];
    bf16* al1 = &As[(wave*2 + 1)*512];
    bf16* bl0 = &Bs[(wave*2    )*512];
    bf16* bl1 = &Bs[(wave*2 + 1)*512];

    for (int k0 = 0; k0 < D_; k0 += 32) {
        gl_lds16(agp0 + k0, al0);
        gl_lds16(agp1 + k0, al1);
        gl_lds16(bgp0 + k0, bl0);
        gl_lds16(bgp1 + k0, bl1);
        __syncthreads();
        v8s af[4], bf[4];
        #pragma unroll
        for (int i = 0; i < 4; i++)
            af[i] = *reinterpret_cast<const v8s*>(&As[(wm*64 + i*16 + l16)*32 + quad*8]);
        #pragma unroll
        for (int j = 0; j < 4; j++)
            bf[j] = *reinterpret_cast<const v8s*>(&Bs[(wn*64 + j*16 + l16)*32 + quad*8]);
        #pragma unroll
        for (int i = 0; i < 4; i++)
            #pragma unroll
            for (int j = 0; j < 4; j++)
                acc[i][j] = __builtin_amdgcn_mfma_f32_16x16x32_bf16(af[i], bf[j], acc[i][j], 0, 0, 0);
        __syncthreads();
    }
    #pragma unroll
    for (int i = 0; i < 4; i++)
        #pragma unroll
        for (int j = 0; j < 4; j++) {
            int n = col0 + wn*64 + j*16 + l16;
            #pragma unroll
            for (int r = 0; r < 4; r++) {
                int m = row0 + wm*64 + i*16 + quad*4 + r;
                outp[(size_t)m*D_ + n] = __float2bfloat16(acc[i][j][r]);
            }
        }
}

// ---- G_h[b] = xb[b] @ A_h  (only 128-row tiles with r0 < sep) ----
__global__ __launch_bounds__(256) void k_gmat(const bf16* __restrict__ xb,
                                              const bf16* __restrict__ AT,
                                              const int* __restrict__ seg,
                                              bf16* __restrict__ G) {
    int b = blockIdx.x;
    int mt = blockIdx.y / 6, nt = blockIdx.y % 6;
    int h = blockIdx.z;
    int sep = seg[b*2];
    int row0 = mt*128;
    if (row0 >= sep) return;
    const bf16* Asrc = xb + (size_t)b*L_*D_;
    const bf16* Bsrc = AT + (size_t)h*D_*D_;          // row v of AT = col v of A
    bf16* outp = G + (size_t)(h*B_ + b)*L_*D_;
    __shared__ bf16 As[128*32];
    __shared__ bf16 Bs[128*32];
    int t = threadIdx.x;
    int wave = t >> 6, lane = t & 63;
    int quad = lane >> 4, l16 = lane & 15;
    int wm = wave >> 1, wn = wave & 1;
    int col0 = nt * 128;

    v4f acc[4][4];
    #pragma unroll
    for (int i = 0; i < 4; i++)
        #pragma unroll
        for (int j = 0; j < 4; j++) acc[i][j] = (v4f){0.f,0.f,0.f,0.f};

    int srow = lane >> 2;
    int skoff = (lane & 3) * 8;
    const bf16* agp0 = Asrc + (size_t)(row0 + wave*32 + srow)*D_ + skoff;
    const bf16* agp1 = agp0 + 16*D_;
    const bf16* bgp0 = Bsrc + (size_t)(col0 + wave*32 + srow)*D_ + skoff;
    const bf16* bgp1 = bgp0 + 16*D_;
    bf16* al0 = &As[(wave*2    )*512];
    bf16* al1 = &As[(wave*2 + 1)*512];
    bf16* bl0 = &Bs[(wave*2    )*512];
    bf16* bl1 = &Bs[(wave*2 + 1)*512];

    for (int k0 = 0; k0 < D_; k0 += 32) {
        gl_lds16(agp0 + k0, al0);
        gl_lds16(agp1 + k0, al1);
        gl_lds16(bgp0 + k0, bl0);
        gl_lds16(bgp1 + k0, bl1);
        __syncthreads();
        v8s af[4], bf[4];
        #pragma unroll
        for (int i = 0; i < 4; i++)
            af[i] = *reinterpret_cast<const v8s*>(&As[(wm*64 + i*16 + l16)*32 + quad*8]);
        #pragma unroll
        for (int j = 0; j < 4; j++)
            bf[j] = *reinterpret_cast<const v8s*>(&Bs[(wn*64 + j*16 + l16)*32 + quad*8]);
        #pragma unroll
        for (int i = 0; i < 4; i++)
            #pragma unroll
            for (int j = 0; j < 4; j++)
                acc[i][j] = __builtin_amdgcn_mfma_f32_16x16x32_bf16(af[i], bf[j], acc[i][j], 0, 0, 0);
        __syncthreads();
    }
    #pragma unroll
    for (int i = 0; i < 4; i++)
        #pragma unroll
        for (int j = 0; j < 4; j++) {
            int n = col0 + wn*64 + j*16 + l16;
            #pragma unroll
            for (int r = 0; r < 4; r++) {
                int m = row0 + wm*64 + i*16 + quad*4 + r;
                outp[(size_t)m*D_ + n] = __float2bfloat16(acc[i][j][r]);
            }
        }
}

// ------ scores via G.x^T: 18 MFMA chains/wave, softmax + gate-reduce ----
__global__ __launch_bounds__(256) void k_score(const bf16* __restrict__ G,
                                               const bf16* __restrict__ xb,
                                               const int* __restrict__ ids,
                                               const int* __restrict__ seg,
                                               const float* __restrict__ gate,
                                               const int* pad_p,
                                               const float* __restrict__ csup,
                                               const float* __restrict__ ccon,
                                               const float* __restrict__ crep,
                                               const float* __restrict__ rcon,
                                               const float* __restrict__ vecs,
                                               float* __restrict__ w_sup,
                                               float* __restrict__ w_rep) {
    int b = blockIdx.x, rt = blockIdx.y;          // x=batch for XCD L2 affinity
    int sep = seg[b*2];
    int r0 = rt*16;
    if (r0 >= sep) return;
    int pad = *pad_p;
    int wave = threadIdx.x >> 6, lane = threadIdx.x & 63;
    int quad = lane >> 4, l16 = lane & 15;
    const float inv  = 0.03608439182435161f;      // 1/sqrt(768)
    int ct0 = (sep + 1) >> 4;                     // first tile containing cols > sep

    int tile[6]; bool act[6];
    #pragma unroll
    for (int i = 0; i < 6; i++) {
        int ctv = ct0 + wave + 4*i;
        act[i] = ctv < 32;
        tile[i] = act[i] ? ctv : 31;
    }
    int qoff = (r0 + l16)*D_ + quad*8;
    int koff[6];
    #pragma unroll
    for (int i = 0; i < 6; i++) koff[i] = (tile[i]*16 + l16)*D_ + quad*8;

    v4f S[6], C[6], R[6];
    #pragma unroll
    for (int i = 0; i < 6; i++) { S[i] = (v4f){0,0,0,0}; C[i] = (v4f){0,0,0,0}; R[i] = (v4f){0,0,0,0}; }

    const bf16* gsup = G + (size_t)(0*B_ + b)*L_*D_;
    const bf16* gcon = G + (size_t)(1*B_ + b)*L_*D_;
    const bf16* grep = G + (size_t)(2*B_ + b)*L_*D_;
    const bf16* xrow = xb + (size_t)b*L_*D_;

    for (int k0 = 0; k0 < D_; k0 += 32) {
        v8s as = *reinterpret_cast<const v8s*>(gsup + qoff + k0);
        v8s ac = *reinterpret_cast<const v8s*>(gcon + qoff + k0);
        v8s ar = *reinterpret_cast<const v8s*>(grep + qoff + k0);
        #pragma unroll
        for (int i = 0; i < 6; i++) {
            v8s kf = *reinterpret_cast<const v8s*>(xrow + koff[i] + k0);
            S[i] = __builtin_amdgcn_mfma_f32_16x16x32_bf16(as, kf, S[i], 0, 0, 0);
            C[i] = __builtin_amdgcn_mfma_f32_16x16x32_bf16(ac, kf, C[i], 0, 0, 0);
            R[i] = __builtin_amdgcn_mfma_f32_16x16x32_bf16(ar, kf, R[i], 0, 0, 0);
        }
    }

    bool opt[6];
    float cs_v[6], cc_v[6], cr_v[6];
    #pragma unroll
    for (int i = 0; i < 6; i++) {
        int c = tile[i]*16 + l16;
        opt[i] = act[i] && (c > sep) && (ids[b*L_ + c] != pad);
        cs_v[i] = csup[b*L_ + c];
        cc_v[i] = ccon[b*L_ + c];
        cr_v[i] = crep[b*L_ + c];
    }
    float rc_r[4];
    #pragma unroll
    for (int r = 0; r < 4; r++) rc_r[r] = rcon[b*L_ + r0 + quad*4 + r];
    float dcon = vecs[3072];

    // assemble final logits in S (sup) and R (rep + tanh(con))
    #pragma unroll
    for (int i = 0; i < 6; i++)
        #pragma unroll
        for (int r = 0; r < 4; r++) {
            float sl = (S[i][r] + cs_v[i]) * inv;
            float cl = fast_tanh((C[i][r] + cc_v[i] + rc_r[r] + dcon) * inv);
            float rl = (R[i][r] + cr_v[i]) * inv + cl;
            S[i][r] = sl; R[i][r] = rl;
        }

    float mxs[4], mxr[4];
    #pragma unroll
    for (int r = 0; r < 4; r++) { mxs[r] = NEGV; mxr[r] = NEGV; }
    #pragma unroll
    for (int i = 0; i < 6; i++)
        #pragma unroll
        for (int r = 0; r < 4; r++) {
            float sv = opt[i] ? S[i][r] : NEGV;
            float rv = opt[i] ? R[i][r] : NEGV;
            mxs[r] = fmaxf(mxs[r], sv);
            mxr[r] = fmaxf(mxr[r], rv);
        }
    #pragma unroll
    for (int d = 1; d < 16; d <<= 1)
        #pragma unroll
        for (int r = 0; r < 4; r++) {
            mxs[r] = fmaxf(mxs[r], __shfl_xor(mxs[r], d));
            mxr[r] = fmaxf(mxr[r], __shfl_xor(mxr[r], d));
        }
    __shared__ float redm[2][16][4];
    __shared__ float reds[2][16][4];
    if (l16 == 0)
        #pragma unroll
        for (int r = 0; r < 4; r++) {
            redm[0][quad*4+r][wave] = mxs[r];
            redm[1][quad*4+r][wave] = mxr[r];
        }
    __syncthreads();
    #pragma unroll
    for (int r = 0; r < 4; r++) {
        int row = quad*4 + r;
        mxs[r] = fmaxf(fmaxf(redm[0][row][0], redm[0][row][1]), fmaxf(redm[0][row][2], redm[0][row][3]));
        mxr[r] = fmaxf(fmaxf(redm[1][row][0], redm[1][row][1]), fmaxf(redm[1][row][2], redm[1][row][3]));
    }

    float ssum[4] = {0,0,0,0}, rsum[4] = {0,0,0,0};
    #pragma unroll
    for (int i = 0; i < 6; i++)
        #pragma unroll
        for (int r = 0; r < 4; r++) {
            float es = opt[i] ? __expf(S[i][r] - mxs[r]) : 0.f;
            float er = opt[i] ? __expf(R[i][r] - mxr[r]) : 0.f;
            S[i][r] = es; R[i][r] = er;
            ssum[r] += es; rsum[r] += er;
        }
    #pragma unroll
    for (int d = 1; d < 16; d <<= 1)
        #pragma unroll
        for (int r = 0; r < 4; r++) {
            ssum[r] += __shfl_xor(ssum[r], d);
            rsum[r] += __shfl_xor(rsum[r], d);
        }
    if (l16 == 0)
        #pragma unroll
        for (int r = 0; r < 4; r++) {
            reds[0][quad*4+r][wave] = ssum[r];
            reds[1][quad*4+r][wave] = rsum[r];
        }
    __syncthreads();
    float gs_[4], gr_[4];
    #pragma unroll
    for (int r = 0; r < 4; r++) {
        int row = quad*4 + r;
        float st = reds[0][row][0] + reds[0][row][1] + reds[0][row][2] + reds[0][row][3];
        float rtot = reds[1][row][0] + reds[1][row][1] + reds[1][row][2] + reds[1][row][3];
        float g = gate[b*L_ + r0 + row];
        gs_[r] = g / st;
        gr_[r] = g / rtot;
    }

    #pragma unroll
    for (int i = 0; i < 6; i++) {
        float cs = 0.f, cr = 0.f;
        #pragma unroll
        for (int r = 0; r < 4; r++) { cs += S[i][r]*gs_[r]; cr += R[i][r]*gr_[r]; }
        cs += __shfl_xor(cs, 16); cs += __shfl_xor(cs, 32);
        cr += __shfl_xor(cr, 16); cr += __shfl_xor(cr, 32);
        if (act[i] && quad == 0) {
            int c = tile[i]*16 + l16;
            atomicAdd(&w_sup[b*L_ + c], cs);
            atomicAdd(&w_rep[b*L_ + c], cr);
        }
    }
}

// ---- 3 gemvs over L: partial per 64-row chunk, atomic into fused[32][2304] --
__global__ __launch_bounds__(256) void k_fused(const float* __restrict__ x,
                                               const float* __restrict__ gate,
                                               const float* __restrict__ wrep,
                                               const float* __restrict__ wsup,
                                               float* __restrict__ fused) {
    int b = blockIdx.x, ch = blockIdx.y, t = threadIdx.x;
    int l0 = ch*64;
    const float* xb_ = x + (size_t)b*L_*D_;
    float a0=0,a1=0,a2=0, r0=0,r1=0,r2=0, s0=0,s1=0,s2=0;
    for (int l = l0; l < l0+64; l++) {
        float g = gate[b*L_+l], wr = wrep[b*L_+l], wv = wsup[b*L_+l];
        if (g == 0.f && wr == 0.f && wv == 0.f) continue;
        float x0 = xb_[l*D_ + t], x1 = xb_[l*D_ + t + 256], x2 = xb_[l*D_ + t + 512];
        a0 += g*x0;  a1 += g*x1;  a2 += g*x2;
        r0 += wr*x0; r1 += wr*x1; r2 += wr*x2;
        s0 += wv*x0; s1 += wv*x1; s2 += wv*x2;
    }
    float* f = fused + (size_t)b*2304;
    atomicAdd(&f[t],        a0); atomicAdd(&f[t+256],      a1); atomicAdd(&f[t+512],      a2);
    atomicAdd(&f[768+t],    r0); atomicAdd(&f[768+t+256],  r1); atomicAdd(&f[768+t+512],  r2);
    atomicAdd(&f[1536+t],   s0); atomicAdd(&f[1536+t+256], s1); atomicAdd(&f[1536+t+512], s2);
}

// ---- MLP layer 1, split-K: 216 blocks, partial sums into h1pre via atomics ----
__global__ __launch_bounds__(256) void k_mlp1(const float* __restrict__ fused,
                                              const float* __restrict__ W1,
                                              float* __restrict__ h1pre) {
    int c0 = blockIdx.x*64, k0 = blockIdx.y*128;
    int t = threadIdx.x;
    __shared__ float fsl[32][132];
    for (int i = t*4; i < 32*128; i += 1024) {
        int b = i >> 7, k = i & 127;
        const float4 v = *reinterpret_cast<const float4*>(&fused[(size_t)b*2304 + k0 + k]);
        fsl[b][k] = v.x; fsl[b][k+1] = v.y; fsl[b][k+2] = v.z; fsl[b][k+3] = v.w;
    }
    __syncthreads();
    int c = c0 + (t & 63), bg = (t >> 6) * 8;
    float acc[8] = {0,0,0,0,0,0,0,0};
    for (int k = 0; k < 128; k++) {
        float w = W1[(size_t)(k0+k)*D_ + c];
        #pragma unroll
        for (int b = 0; b < 8; b++) acc[b] += fsl[bg+b][k] * w;
    }
    #pragma unroll
    for (int b = 0; b < 8; b++) atomicAdd(&h1pre[(size_t)(bg+b)*D_ + c], acc[b]);
}

// ---- MLP layer 2, split-K: relu(h1pre+b1) on load; partials into opre ----
__global__ __launch_bounds__(256) void k_mlp2(const float* __restrict__ h1pre,
                                              const float* __restrict__ b1,
                                              const float* __restrict__ W2,
                                              float* __restrict__ opre) {
    int c0 = blockIdx.x*64, k0 = blockIdx.y*128;
    int t = threadIdx.x;
    __shared__ float fsl[32][132];
    for (int i = t*4; i < 32*128; i += 1024) {
        int b = i >> 7, k = i & 127;
        const float4 v = *reinterpret_cast<const float4*>(&h1pre[(size_t)b*D_ + k0 + k]);
        const float4 bb = *reinterpret_cast<const float4*>(&b1[k0 + k]);
        fsl[b][k]   = fmaxf(v.x + bb.x, 0.f);
        fsl[b][k+1] = fmaxf(v.y + bb.y, 0.f);
        fsl[b][k+2] = fmaxf(v.z + bb.z, 0.f);
        fsl[b][k+3] = fmaxf(v.w + bb.w, 0.f);
    }
    __syncthreads();
    int c = c0 + (t & 63), bg = (t >> 6) * 8;
    float acc[8] = {0,0,0,0,0,0,0,0};
    for (int k = 0; k < 128; k++) {
        float w = W2[(size_t)(k0+k)*D_ + c];
        #pragma unroll
        for (int b = 0; b < 8; b++) acc[b] += fsl[bg+b][k] * w;
    }
    #pragma unroll
    for (int b = 0; b < 8; b++) atomicAdd(&opre[(size_t)(bg+b)*D_ + c], acc[b]);
}

// ---- bias2 + LayerNorm: one block per batch ----
__global__ __launch_bounds__(256) void k_ln(const float* __restrict__ opre,
                                            const float* __restrict__ b2,
                                            const float* __restrict__ lng,
                                            const float* __restrict__ lnb,
                                            float* __restrict__ out) {
    int b = blockIdx.x, t = threadIdx.x;
    __shared__ float red[256];
    float v0 = opre[(size_t)b*D_ + t]       + b2[t];
    float v1 = opre[(size_t)b*D_ + t + 256] + b2[t+256];
    float v2 = opre[(size_t)b*D_ + t + 512] + b2[t+512];
    float sum = v0+v1+v2, sq = v0*v0+v1*v1+v2*v2;
    red[t] = sum; __syncthreads();
    for (int s = 128; s; s >>= 1) { if (t < s) red[t] += red[t+s]; __syncthreads(); }
    sum = red[0]; __syncthreads();
    red[t] = sq; __syncthreads();
    for (int s = 128; s; s >>= 1) { if (t < s) red[t] += red[t+s]; __syncthreads(); }
    sq = red[0];
    float mu = sum / 768.f;
    float var = sq / 768.f - mu*mu;
    float rstd = rsqrtf(var + 1e-5f);
    out[(size_t)b*D_ + t]       = (v0-mu)*rstd*lng[t]     + lnb[t];
    out[(size_t)b*D_ + t + 256] = (v1-mu)*rstd*lng[t+256] + lnb[t+256];
    out[(size_t)b*D_ + t + 512] = (v2-mu)*rstd*lng[t+512] + lnb[t+512];
}

extern "C" void kernel_launch(void* const* d_in, const int* in_sizes, int n_in,
                              void* d_out, int out_size, void* d_ws, size_t ws_size,
                              hipStream_t stream) {
    const float* x      = (const float*)d_in[0];
    const int*   ids    = (const int*)d_in[1];
    const int*   pad_p  = (const int*)d_in[2];
    const int*   sep_p  = (const int*)d_in[3];
    const float* W_anom = (const float*)d_in[4];
    const float* b_anom = (const float*)d_in[5];
    const float* Wq_sup = (const float*)d_in[6];  const float* bq_sup = (const float*)d_in[7];
    const float* Wk_sup = (const float*)d_in[8];  const float* bk_sup = (const float*)d_in[9];
    const float* Wq_con = (const float*)d_in[10]; const float* bq_con = (const float*)d_in[11];
    const float* Wk_con = (const float*)d_in[12]; const float* bk_con = (const float*)d_in[13];
    const float* Wq_rep = (const float*)d_in[14]; const float* bq_rep = (const float*)d_in[15];
    const float* Wk_rep = (const float*)d_in[16]; const float* bk_rep = (const float*)d_in[17];
    const float* W1     = (const float*)d_in[18]; const float* b1     = (const float*)d_in[19];
    const float* W2     = (const float*)d_in[20]; const float* b2     = (const float*)d_in[21];
    const float* lng    = (const float*)d_in[22]; const float* lnb    = (const float*)d_in[23];
    float* out = (float*)d_out;

    char* w = (char*)d_ws;
    bf16*  xb    = (bf16*)(w);                      // 25,165,824
    bf16*  wb6   = (bf16*)(w + 25165824);           //  7,077,888
    bf16*  AT    = (bf16*)(w + 32243712);           //  3,538,944
    bf16*  G     = (bf16*)(w + 35782656);           // 75,497,472
    float* vecs  = (float*)(w + 111280128);         //     16,384 (vc_sup|vc_con|vc_rep|u_con|d_con)
    float* anom  = (float*)(w + 111296512);         //     65,536
    float* gate  = (float*)(w + 111362048);         //     65,536
    float* csup  = (float*)(w + 111427584);         //     65,536
    float* ccon  = (float*)(w + 111493120);         //     65,536
    float* crep  = (float*)(w + 111558656);         //     65,536
    float* rcon  = (float*)(w + 111624192);         //     65,536
    float* wsup  = (float*)(w + 111689728);         //     65,536
    float* wrep  = (float*)(w + 111755264);         //     65,536
    float* fused = (float*)(w + 111820800);         //    294,912
    float* h1pre = (float*)(w + 112115712);         //     98,304
    float* opre  = (float*)(w + 112214016);         //     98,304
    int*   seg   = (int*)  (w + 112312320);         //        256

    k_seg<<<B_, 256, 0, stream>>>(ids, pad_p, sep_p, seg);
    k_cast_x<<<4096, 256, 0, stream>>>(x, xb);
    k_castw6<<<dim3(D_*D_/256, 6), 256, 0, stream>>>(Wq_sup, Wk_sup, Wq_con, Wk_con, Wq_rep, Wk_rep, wb6);
    k_vecs<<<769, 256, 0, stream>>>(Wk_sup, bq_sup, Wk_con, bq_con, Wk_rep, bq_rep, Wq_con, bk_con, vecs);
    k_rowdots<<<4096, 256, 0, stream>>>(x, W_anom, b_anom, vecs, anom, csup, ccon, crep, rcon);
    k_gate<<<B_, 256, 0, stream>>>(anom, ids, seg, pad_p, gate);
    // zero: wsup + wrep + fused + h1pre + opre (contiguous, 622,592 B)
    hipMemsetAsync(wsup, 0, 622592, stream);
    k_wqk<<<dim3(6, 6, 3), 256, 0, stream>>>(wb6, AT);
    k_gmat<<<dim3(B_, 24, 3), 256, 0, stream>>>(xb, AT, seg, G);
    k_score<<<dim3(B_, 32), 256, 0, stream>>>(G, xb, ids, seg, gate, pad_p,
                                              csup, ccon, crep, rcon, vecs, wsup, wrep);
    k_fused<<<dim3(B_, 8), 256, 0, stream>>>(x, gate, wrep, wsup, fused);
    k_mlp1<<<dim3(12, 18), 256, 0, stream>>>(fused, W1, h1pre);
    k_mlp2<<<dim3(12, 6), 256, 0, stream>>>(h1pre, b1, W2, opre);
    k_ln<<<B_, 256, 0, stream>>>(opre, b2, lng, lnb, out);
}